// Round 1
// baseline (791.381 us; speedup 1.0000x reference)
//
#include <hip/hip_runtime.h>

typedef _Float16 f16;
typedef _Float16 f16x4 __attribute__((ext_vector_type(4)));
typedef _Float16 f16x8 __attribute__((ext_vector_type(8)));
typedef float f32x4 __attribute__((ext_vector_type(4)));

#define B_ 4
#define H_ 16
#define S_ 2048
#define D_ 128

#define KSTR 136   // K lds row stride in f16 elems (272B: 16B aligned, 2-way banks)
#define VSTR 56    // Vt lds row stride (112B: 16B aligned, 2-way banks)
#define PSTR 56    // P lds row stride

__global__ __launch_bounds__(256, 2)
void fattn_kernel(const float* __restrict__ Qg, const float* __restrict__ Kg,
                  const float* __restrict__ Vg, float* __restrict__ Og)
{
    __shared__ f16 Klds[32 * KSTR];
    __shared__ f16 Vt[128 * VSTR];
    __shared__ f16 Plds[4][16 * PSTR];

    const int qt   = blockIdx.x;   // 0..31  (q tile of 64 rows)
    const int bh   = blockIdx.y;   // 0..63
    const int tid  = threadIdx.x;
    const int wave = tid >> 6;
    const int lane = tid & 63;
    const int lr   = lane & 15;    // 0..15
    const int lg   = lane >> 4;    // 0..3

    const int q0  = qt * 64;
    const int qw0 = q0 + wave * 16;    // this wave's first q row

    const size_t base = (size_t)bh * S_ * D_;
    const float* Qb = Qg + base;
    const float* Kb = Kg + base;
    const float* Vb = Vg + base;
    float*       Ob = Og + base;

    // ---- load Q fragments into registers, pre-scaled by 1/sqrt(128)*log2(e)
    const float qmul = 0.08838834764831845f * 1.4426950408889634f;
    f16x8 qf[4];
    {
        const float* Qrow = Qb + (size_t)(qw0 + lr) * D_;
        #pragma unroll
        for (int kc = 0; kc < 4; ++kc) {
            const float4 a = *(const float4*)(Qrow + kc * 32 + lg * 8);
            const float4 b = *(const float4*)(Qrow + kc * 32 + lg * 8 + 4);
            f16x8 q;
            q[0] = (f16)(a.x * qmul); q[1] = (f16)(a.y * qmul);
            q[2] = (f16)(a.z * qmul); q[3] = (f16)(a.w * qmul);
            q[4] = (f16)(b.x * qmul); q[5] = (f16)(b.y * qmul);
            q[6] = (f16)(b.z * qmul); q[7] = (f16)(b.w * qmul);
            qf[kc] = q;
        }
    }

    f32x4 acc[8];
    #pragma unroll
    for (int d0 = 0; d0 < 8; ++d0) acc[d0] = (f32x4){0.f, 0.f, 0.f, 0.f};
    float m_i[4], l_i[4];
    #pragma unroll
    for (int i = 0; i < 4; ++i) { m_i[i] = -1e30f; l_i[i] = 0.f; }

    const int nkt = 2 * qt + 2;     // causal: tiles 0 .. (q0+63)/32
    for (int kt = 0; kt < nkt; ++kt) {
        const int k0 = kt * 32;
        __syncthreads();
        // ---- stage K tile [32][128] and V^T tile [128][32] (fp32 -> f16)
        #pragma unroll
        for (int r = 0; r < 4; ++r) {
            const int idx = tid + r * 256;   // float4 index, 0..1023
            const int row = idx >> 5;        // key row 0..31
            const int c4  = idx & 31;        // float4 col
            const float4 kv = *(const float4*)(Kb + (size_t)(k0 + row) * D_ + c4 * 4);
            const float4 vv = *(const float4*)(Vb + (size_t)(k0 + row) * D_ + c4 * 4);
            f16x4 kk;
            kk[0] = (f16)kv.x; kk[1] = (f16)kv.y; kk[2] = (f16)kv.z; kk[3] = (f16)kv.w;
            *reinterpret_cast<f16x4*>(&Klds[row * KSTR + c4 * 4]) = kk;
            Vt[(c4 * 4 + 0) * VSTR + row] = (f16)vv.x;
            Vt[(c4 * 4 + 1) * VSTR + row] = (f16)vv.y;
            Vt[(c4 * 4 + 2) * VSTR + row] = (f16)vv.z;
            Vt[(c4 * 4 + 3) * VSTR + row] = (f16)vv.w;
        }
        __syncthreads();

        if (k0 <= qw0 + 15) {   // tile not fully masked for this wave
            // ---- S = Q K^T  (two 16x16 col-tiles, K-dim 128 in 4 chunks)
            f32x4 s[2];
            s[0] = (f32x4){0.f, 0.f, 0.f, 0.f};
            s[1] = (f32x4){0.f, 0.f, 0.f, 0.f};
            #pragma unroll
            for (int t = 0; t < 2; ++t) {
                #pragma unroll
                for (int kc = 0; kc < 4; ++kc) {
                    const f16x8 kbf = *reinterpret_cast<const f16x8*>(
                        &Klds[(t * 16 + lr) * KSTR + kc * 32 + lg * 8]);
                    s[t] = __builtin_amdgcn_mfma_f32_16x16x32_f16(qf[kc], kbf, s[t], 0, 0, 0);
                }
            }
            // ---- causal mask
            if (k0 + 31 > qw0) {
                #pragma unroll
                for (int t = 0; t < 2; ++t) {
                    const int kg = k0 + t * 16 + lr;
                    #pragma unroll
                    for (int i = 0; i < 4; ++i) {
                        const int qg = qw0 + lg * 4 + i;
                        if (kg > qg) s[t][i] = -1e30f;
                    }
                }
            }
            // ---- online softmax (rows spread over 16-lane groups)
            float rmax[4], rs[4], alpha[4];
            #pragma unroll
            for (int i = 0; i < 4; ++i) rmax[i] = fmaxf(s[0][i], s[1][i]);
            #pragma unroll
            for (int st = 8; st >= 1; st >>= 1) {
                #pragma unroll
                for (int i = 0; i < 4; ++i)
                    rmax[i] = fmaxf(rmax[i], __shfl_xor(rmax[i], st, 16));
            }
            f32x4 p[2];
            #pragma unroll
            for (int i = 0; i < 4; ++i) {
                const float mn = fmaxf(m_i[i], rmax[i]);
                alpha[i] = exp2f(m_i[i] - mn);
                m_i[i] = mn;
                p[0][i] = exp2f(s[0][i] - mn);
                p[1][i] = exp2f(s[1][i] - mn);
                rs[i] = p[0][i] + p[1][i];
            }
            #pragma unroll
            for (int st = 8; st >= 1; st >>= 1) {
                #pragma unroll
                for (int i = 0; i < 4; ++i)
                    rs[i] += __shfl_xor(rs[i], st, 16);
            }
            #pragma unroll
            for (int i = 0; i < 4; ++i) l_i[i] = l_i[i] * alpha[i] + rs[i];
            #pragma unroll
            for (int d0 = 0; d0 < 8; ++d0) {
                #pragma unroll
                for (int i = 0; i < 4; ++i) acc[d0][i] *= alpha[i];
            }
            // ---- P (C/D layout) -> LDS -> A-fragment layout
            f16* Pw = &Plds[wave][0];
            #pragma unroll
            for (int t = 0; t < 2; ++t) {
                #pragma unroll
                for (int i = 0; i < 4; ++i)
                    Pw[(lg * 4 + i) * PSTR + t * 16 + lr] = (f16)p[t][i];
            }
            const f16x8 pa = *reinterpret_cast<const f16x8*>(&Pw[lr * PSTR + lg * 8]);
            // ---- O += P V
            #pragma unroll
            for (int d0 = 0; d0 < 8; ++d0) {
                const f16x8 vb = *reinterpret_cast<const f16x8*>(
                    &Vt[(d0 * 16 + lr) * VSTR + lg * 8]);
                acc[d0] = __builtin_amdgcn_mfma_f32_16x16x32_f16(pa, vb, acc[d0], 0, 0, 0);
            }
        }
    }

    // ---- epilogue: O / l
    float rl[4];
    #pragma unroll
    for (int i = 0; i < 4; ++i) rl[i] = 1.f / l_i[i];
    #pragma unroll
    for (int d0 = 0; d0 < 8; ++d0) {
        #pragma unroll
        for (int i = 0; i < 4; ++i) {
            const int row = qw0 + lg * 4 + i;
            Ob[(size_t)row * D_ + d0 * 16 + lr] = acc[d0][i] * rl[i];
        }
    }
}

extern "C" void kernel_launch(void* const* d_in, const int* in_sizes, int n_in,
                              void* d_out, int out_size, void* d_ws, size_t ws_size,
                              hipStream_t stream) {
    (void)in_sizes; (void)n_in; (void)d_ws; (void)ws_size; (void)out_size;
    const float* Q = (const float*)d_in[0];
    const float* K = (const float*)d_in[1];
    const float* V = (const float*)d_in[2];
    float* O = (float*)d_out;
    dim3 grid(S_ / 64, B_ * H_);
    fattn_kernel<<<grid, 256, 0, stream>>>(Q, K, V, O);
}

// Round 4
// 238.513 us; speedup vs baseline: 3.3180x; 3.3180x over previous
//
#include <hip/hip_runtime.h>

typedef _Float16 f16;
typedef _Float16 f16x8 __attribute__((ext_vector_type(8)));
typedef float    f32x16 __attribute__((ext_vector_type(16)));
typedef int      i32x4 __attribute__((ext_vector_type(4)));

#define B_ 4
#define H_ 16
#define S_ 2048
#define D_ 128
#define KSTR 136      // K lds row stride (f16 elems): 272B, 16B-aligned, min-aliasing b128
#define VTSTR 72      // V^T lds row stride (f16 elems): 144B, 16B-aligned, min-aliasing b128

union U4 { i32x4 i; f16x8 h; };

__device__ __forceinline__ unsigned pk2(float a, float b) {
    auto v = __builtin_amdgcn_cvt_pkrtz(a, b);   // __fp16 ext_vector(2)
    return __builtin_bit_cast(unsigned, v);
}

__global__ __launch_bounds__(256, 2)
void fattn3(const float* __restrict__ Qg, const float* __restrict__ Kg,
            const float* __restrict__ Vg, float* __restrict__ Og)
{
    __shared__ __align__(16) f16 Klds[64 * KSTR];    // 17408 B
    __shared__ __align__(16) f16 Vt[128 * VTSTR];    // 18432 B  (V^T: [d][k])

    // XCD-clustered remap: all 16 q-tiles of one bh land on one XCD (L2 reuse of K/V)
    const int id  = blockIdx.x;
    const int xcd = id & 7;
    const int w   = id >> 3;
    const int qt  = w & 15;          // 0..15 (128 q rows per block)
    const int bh  = xcd + 8 * (w >> 4);

    const int tid  = threadIdx.x;
    const int lane = tid & 63;
    const int wv   = tid >> 6;       // 4 waves
    const int l31  = lane & 31;
    const int h    = lane >> 5;

    const int qw0 = qt * 128 + wv * 32;      // wave's first q row
    const int qg  = qw0 + l31;               // this lane's q row (for S^T / softmax)

    const size_t base = (size_t)bh * S_ * D_;
    const float* Qb = Qg + base;
    const float* Kb = Kg + base;
    const float* Vb = Vg + base;
    float*       Ob = Og + base;

    // ---- Q fragments in registers (B-operand: col=q=l31, k-dim d = dc*16 + 8h + j)
    const float qmul = 0.08838834764831845f * 1.4426950408889634f;  // 1/sqrt(128)*log2e
    f16x8 qf[8];
    {
        const float* Qrow = Qb + (size_t)(qw0 + l31) * D_;
        #pragma unroll
        for (int dc = 0; dc < 8; ++dc) {
            const float4 a = *(const float4*)(Qrow + dc * 16 + h * 8);
            const float4 b = *(const float4*)(Qrow + dc * 16 + h * 8 + 4);
            f16x8 q;
            q[0] = (f16)(a.x * qmul); q[1] = (f16)(a.y * qmul);
            q[2] = (f16)(a.z * qmul); q[3] = (f16)(a.w * qmul);
            q[4] = (f16)(b.x * qmul); q[5] = (f16)(b.y * qmul);
            q[6] = (f16)(b.z * qmul); q[7] = (f16)(b.w * qmul);
            qf[dc] = q;
        }
    }

    f32x16 acc[4];
    #pragma unroll
    for (int dt = 0; dt < 4; ++dt)
        #pragma unroll
        for (int r = 0; r < 16; ++r) acc[dt][r] = 0.f;
    float m_i = -1e30f, l_i = 0.f;

    const int nkt = 2 * qt + 2;
    for (int kt = 0; kt < nkt; ++kt) {
        const int k0 = kt * 64;
        __syncthreads();
        // ---- stage K [64][KSTR] row-major; V^T [128][VTSTR] via transpose-at-read
        #pragma unroll
        for (int it = 0; it < 4; ++it) {
            const int idx = tid + it * 256;     // 0..1023
            // K: row-major f16x8 chunks
            const int krow = idx >> 4;          // 0..63
            const int c8   = idx & 15;
            const float* kp = Kb + (size_t)(k0 + krow) * D_ + c8 * 8;
            const float4 ka  = *(const float4*)kp;
            const float4 kb4 = *(const float4*)(kp + 4);
            f16x8 kh;
            kh[0] = (f16)ka.x;  kh[1] = (f16)ka.y;  kh[2] = (f16)ka.z;  kh[3] = (f16)ka.w;
            kh[4] = (f16)kb4.x; kh[5] = (f16)kb4.y; kh[6] = (f16)kb4.z; kh[7] = (f16)kb4.w;
            *(f16x8*)&Klds[krow * KSTR + c8 * 8] = kh;
            // V^T: thread reads 8 k-consecutive elems of column d (coalesced per step),
            // writes one b128 along the Vt row
            const int d  = idx & 127;
            const int k8 = idx >> 7;            // 0..7
            const float* vp = Vb + (size_t)(k0 + k8 * 8) * D_ + d;
            f16x8 vh;
            #pragma unroll
            for (int e = 0; e < 8; ++e) vh[e] = (f16)vp[(size_t)e * D_];
            *(f16x8*)&Vt[d * VTSTR + k8 * 8] = vh;
        }
        __syncthreads();

        if (k0 <= qw0 + 31) {
            const bool u1ok = (k0 + 32 <= qw0 + 31);
            // ---- swapped QK^T: S^T[k][q] = mfma(K_frag, Q_frag); lane: q=l31, k=(r&3)+8*(r>>2)+4h
            f32x16 sv[2];
            #pragma unroll
            for (int u = 0; u < 2; ++u) {
                if (u == 0 || u1ok) {
                    f32x16 a;
                    #pragma unroll
                    for (int r = 0; r < 16; ++r) a[r] = 0.f;
                    #pragma unroll
                    for (int dc = 0; dc < 8; ++dc) {
                        const f16x8 kf = *(const f16x8*)&Klds[(u * 32 + l31) * KSTR + dc * 16 + h * 8];
                        a = __builtin_amdgcn_mfma_f32_32x32x16_f16(kf, qf[dc], a, 0, 0, 0);
                    }
                    sv[u] = a;
                } else {
                    #pragma unroll
                    for (int r = 0; r < 16; ++r) sv[u][r] = -1e30f;
                }
            }
            // ---- causal mask
            if (k0 + 63 > qw0) {
                #pragma unroll
                for (int u = 0; u < 2; ++u)
                    #pragma unroll
                    for (int r = 0; r < 16; ++r) {
                        const int kg = k0 + u * 32 + (r & 3) + 8 * (r >> 2) + 4 * h;
                        if (kg > qg) sv[u][r] = -1e30f;
                    }
            }
            // ---- online softmax: row q=l31 split across lane^32 partner
            float mx = sv[0][0];
            #pragma unroll
            for (int r = 1; r < 16; ++r) mx = fmaxf(mx, sv[0][r]);
            #pragma unroll
            for (int r = 0; r < 16; ++r) mx = fmaxf(mx, sv[1][r]);
            mx = fmaxf(mx, __shfl_xor(mx, 32));
            // defer-max (T13): skip O-rescale while growth <= 8 (p bounded by 2^8, f16-safe)
            if (!__all(mx - m_i <= 8.0f)) {
                const float mn = fmaxf(m_i, mx);
                const float al = exp2f(m_i - mn);
                m_i = mn;
                l_i *= al;
                float arow[16];
                #pragma unroll
                for (int r = 0; r < 16; ++r)
                    arow[r] = __shfl(al, (r & 3) + 8 * (r >> 2) + 4 * h);
                #pragma unroll
                for (int dt = 0; dt < 4; ++dt)
                    #pragma unroll
                    for (int r = 0; r < 16; ++r) acc[dt][r] *= arow[r];
            }
            float rs = 0.f;
            #pragma unroll
            for (int u = 0; u < 2; ++u)
                #pragma unroll
                for (int r = 0; r < 16; ++r) {
                    sv[u][r] = exp2f(sv[u][r] - m_i);
                    rs += sv[u][r];
                }
            rs += __shfl_xor(rs, 32);
            l_i += rs;
            // ---- P (f32, C/D layout) -> f16 A-frags via pack + cross-half exchange
            U4 pa[4];
            #pragma unroll
            for (int u = 0; u < 2; ++u) {
                unsigned dwp[8];
                #pragma unroll
                for (int m = 0; m < 8; ++m) dwp[m] = pk2(sv[u][2 * m], sv[u][2 * m + 1]);
                #pragma unroll
                for (int hf = 0; hf < 2; ++hf) {   // ks = 2u + hf
                    const unsigned a0 = dwp[hf * 4 + 0], a1 = dwp[hf * 4 + 1];
                    const unsigned b0 = dwp[hf * 4 + 2], b1 = dwp[hf * 4 + 3];
                    const unsigned sa0 = (unsigned)__shfl_xor((int)a0, 32);
                    const unsigned sa1 = (unsigned)__shfl_xor((int)a1, 32);
                    const unsigned sb0 = (unsigned)__shfl_xor((int)b0, 32);
                    const unsigned sb1 = (unsigned)__shfl_xor((int)b1, 32);
                    i32x4 d;
                    d[0] = h ? (int)sb0 : (int)a0;
                    d[1] = h ? (int)sb1 : (int)a1;
                    d[2] = h ? (int)b0  : (int)sa0;
                    d[3] = h ? (int)b1  : (int)sa1;
                    pa[u * 2 + hf].i = d;
                }
            }
            // ---- PV: B-frag = contiguous 8 k along a Vt row (min-aliasing b128 reads)
            #pragma unroll
            for (int dt = 0; dt < 4; ++dt) {
                const f16* vrow = &Vt[(dt * 32 + l31) * VTSTR + h * 8];
                const f16x8 vb0 = *(const f16x8*)(vrow + 0);
                const f16x8 vb1 = *(const f16x8*)(vrow + 16);
                acc[dt] = __builtin_amdgcn_mfma_f32_32x32x16_f16(pa[0].h, vb0, acc[dt], 0, 0, 0);
                acc[dt] = __builtin_amdgcn_mfma_f32_32x32x16_f16(pa[1].h, vb1, acc[dt], 0, 0, 0);
                if (u1ok) {
                    const f16x8 vb2 = *(const f16x8*)(vrow + 32);
                    const f16x8 vb3 = *(const f16x8*)(vrow + 48);
                    acc[dt] = __builtin_amdgcn_mfma_f32_32x32x16_f16(pa[2].h, vb2, acc[dt], 0, 0, 0);
                    acc[dt] = __builtin_amdgcn_mfma_f32_32x32x16_f16(pa[3].h, vb3, acc[dt], 0, 0, 0);
                }
            }
        }
    }

    // ---- epilogue: O = acc / l   (row = (r&3)+8*(r>>2)+4h, col = dt*32 + l31)
    float li[16];
    #pragma unroll
    for (int r = 0; r < 16; ++r) {
        const float lv = __shfl(l_i, (r & 3) + 8 * (r >> 2) + 4 * h);
        li[r] = 1.0f / lv;
    }
    #pragma unroll
    for (int dt = 0; dt < 4; ++dt)
        #pragma unroll
        for (int r = 0; r < 16; ++r) {
            const int row = qw0 + (r & 3) + 8 * (r >> 2) + 4 * h;
            Ob[(size_t)row * D_ + dt * 32 + l31] = acc[dt][r] * li[r];
        }
}

extern "C" void kernel_launch(void* const* d_in, const int* in_sizes, int n_in,
                              void* d_out, int out_size, void* d_ws, size_t ws_size,
                              hipStream_t stream) {
    (void)in_sizes; (void)n_in; (void)d_ws; (void)ws_size; (void)out_size;
    const float* Q = (const float*)d_in[0];
    const float* K = (const float*)d_in[1];
    const float* V = (const float*)d_in[2];
    float* O = (float*)d_out;
    fattn3<<<dim3((S_ / 128) * B_ * H_), dim3(256), 0, stream>>>(Q, K, V, O);
}

// Round 5
// 237.804 us; speedup vs baseline: 3.3279x; 1.0030x over previous
//
#include <hip/hip_runtime.h>

typedef _Float16 f16;
typedef _Float16 f16x8 __attribute__((ext_vector_type(8)));
typedef float    f32x16 __attribute__((ext_vector_type(16)));
typedef int      i32x4 __attribute__((ext_vector_type(4)));

#define B_ 4
#define H_ 16
#define S_ 2048
#define D_ 128
#define KVB 32
#define KSTR 136      // 272B = 17x16B slots, 17%8=1 -> min-aliasing b128
#define VTSTR 40      // 80B  =  5x16B slots,  5%8=5 -> min-aliasing b128

union U4 { i32x4 i; f16x8 h; };

__device__ __forceinline__ unsigned pk2(float a, float b) {
    auto v = __builtin_amdgcn_cvt_pkrtz(a, b);
    return __builtin_bit_cast(unsigned, v);
}

__global__ __launch_bounds__(256, 3)
void fattn4(const float* __restrict__ Qg, const float* __restrict__ Kg,
            const float* __restrict__ Vg, float* __restrict__ Og)
{
    __shared__ __align__(16) f16 Klds[KVB * KSTR];   // 8704 B
    __shared__ __align__(16) f16 Vt[128 * VTSTR];    // 10240 B

    // XCD-clustered + LPT: qt descending in dispatch order, all 16 q-tiles of a bh on one XCD
    const int id  = blockIdx.x;
    const int xcd = id & 7;
    const int w   = id >> 3;
    const int qt  = 15 - (w & 15);       // big blocks dispatched first
    const int bh  = xcd + 8 * (w >> 4);

    const int tid  = threadIdx.x;
    const int lane = tid & 63;
    const int wv   = tid >> 6;
    const int l31  = lane & 31;
    const int h    = lane >> 5;

    const int qw0 = qt * 128 + wv * 32;
    const int qg  = qw0 + l31;

    const size_t base = (size_t)bh * S_ * D_;
    const float* Qb = Qg + base;
    const float* Kb = Kg + base;
    const float* Vb = Vg + base;
    float*       Ob = Og + base;

    // staging addresses (per thread, fixed across tiles)
    const int sK_row = tid >> 4;            // 0..15 (+16 on second chunk? no: idx>>4 for idx=tid, tid+256)
    // we recompute per-chunk below for clarity

    const int nkt = 4 * qt + 4;

    // ---- prefetch registers for one KV tile
    float4 kr[4];
    float  vr[16];

    auto issue = [&](int kt) {
        const int k0n = kt * KVB;
        #pragma unroll
        for (int it = 0; it < 2; ++it) {
            const int idx  = tid + it * 256;        // 0..511
            const int krow = idx >> 4;              // 0..31
            const int c8   = idx & 15;
            const float* kp = Kb + (size_t)(k0n + krow) * D_ + c8 * 8;
            kr[it * 2]     = *(const float4*)kp;
            kr[it * 2 + 1] = *(const float4*)(kp + 4);
            const int d  = idx & 127;
            const int k8 = idx >> 7;                // 0..3
            const float* vp = Vb + (size_t)(k0n + k8 * 8) * D_ + d;
            #pragma unroll
            for (int e = 0; e < 8; ++e) vr[it * 8 + e] = vp[(size_t)e * D_];
        }
    };
    auto writeLds = [&]() {
        #pragma unroll
        for (int it = 0; it < 2; ++it) {
            const int idx  = tid + it * 256;
            const int krow = idx >> 4;
            const int c8   = idx & 15;
            const float4 ka  = kr[it * 2];
            const float4 kb4 = kr[it * 2 + 1];
            f16x8 kh;
            kh[0] = (f16)ka.x;  kh[1] = (f16)ka.y;  kh[2] = (f16)ka.z;  kh[3] = (f16)ka.w;
            kh[4] = (f16)kb4.x; kh[5] = (f16)kb4.y; kh[6] = (f16)kb4.z; kh[7] = (f16)kb4.w;
            *(f16x8*)&Klds[krow * KSTR + c8 * 8] = kh;
            const int d  = idx & 127;
            const int k8 = idx >> 7;
            f16x8 vh;
            #pragma unroll
            for (int e = 0; e < 8; ++e) vh[e] = (f16)vr[it * 8 + e];
            *(f16x8*)&Vt[d * VTSTR + k8 * 8] = vh;
        }
    };

    // ---- Q fragments (B-operand: col=q=l31, k-dim d = dc*16 + 8h + j), pre-scaled
    const float qmul = 0.08838834764831845f * 1.4426950408889634f;
    issue(0);
    f16x8 qf[8];
    {
        const float* Qrow = Qb + (size_t)(qw0 + l31) * D_;
        #pragma unroll
        for (int dc = 0; dc < 8; ++dc) {
            const float4 a = *(const float4*)(Qrow + dc * 16 + h * 8);
            const float4 b = *(const float4*)(Qrow + dc * 16 + h * 8 + 4);
            f16x8 q;
            q[0] = (f16)(a.x * qmul); q[1] = (f16)(a.y * qmul);
            q[2] = (f16)(a.z * qmul); q[3] = (f16)(a.w * qmul);
            q[4] = (f16)(b.x * qmul); q[5] = (f16)(b.y * qmul);
            q[6] = (f16)(b.z * qmul); q[7] = (f16)(b.w * qmul);
            qf[dc] = q;
        }
    }

    f32x16 acc[4];
    #pragma unroll
    for (int dt = 0; dt < 4; ++dt)
        #pragma unroll
        for (int r = 0; r < 16; ++r) acc[dt][r] = 0.f;
    float m_i = -1e30f, l_i = 0.f;

    for (int kt = 0; kt < nkt; ++kt) {
        const int k0 = kt * KVB;
        __syncthreads();          // prev-tile consumers done; vmcnt drain = prefetched loads landed
        writeLds();
        __syncthreads();
        if (kt + 1 < nkt) issue(kt + 1);   // regs only; flies under compute below

        if (k0 <= qw0 + 31) {
            // ---- swapped QK^T: S^T, lane: q=l31, k=(r&3)+8*(r>>2)+4h
            f32x16 sv;
            #pragma unroll
            for (int r = 0; r < 16; ++r) sv[r] = 0.f;
            #pragma unroll
            for (int dc = 0; dc < 8; ++dc) {
                const f16x8 kf = *(const f16x8*)&Klds[l31 * KSTR + dc * 16 + h * 8];
                sv = __builtin_amdgcn_mfma_f32_32x32x16_f16(kf, qf[dc], sv, 0, 0, 0);
            }
            // ---- causal mask
            if (k0 + 31 > qw0) {
                #pragma unroll
                for (int r = 0; r < 16; ++r) {
                    const int kg = k0 + (r & 3) + 8 * (r >> 2) + 4 * h;
                    if (kg > qg) sv[r] = -1e30f;
                }
            }
            // ---- online softmax (row q=l31, split across lane^32)
            float mx = sv[0];
            #pragma unroll
            for (int r = 1; r < 16; ++r) mx = fmaxf(mx, sv[r]);
            mx = fmaxf(mx, __shfl_xor(mx, 32));
            if (!__all(mx - m_i <= 8.0f)) {       // defer-max (T13)
                const float mn = fmaxf(m_i, mx);
                const float al = exp2f(m_i - mn);
                m_i = mn;
                l_i *= al;
                float arow[16];
                #pragma unroll
                for (int r = 0; r < 16; ++r)
                    arow[r] = __shfl(al, (r & 3) + 8 * (r >> 2) + 4 * h);
                #pragma unroll
                for (int dt = 0; dt < 4; ++dt)
                    #pragma unroll
                    for (int r = 0; r < 16; ++r) acc[dt][r] *= arow[r];
            }
            float rs = 0.f;
            #pragma unroll
            for (int r = 0; r < 16; ++r) {
                sv[r] = exp2f(sv[r] - m_i);
                rs += sv[r];
            }
            rs += __shfl_xor(rs, 32);
            l_i += rs;
            // ---- P -> f16 A-frags (pack + cross-half exchange)
            U4 pa[2];
            {
                unsigned dwp[8];
                #pragma unroll
                for (int m = 0; m < 8; ++m) dwp[m] = pk2(sv[2 * m], sv[2 * m + 1]);
                #pragma unroll
                for (int hf = 0; hf < 2; ++hf) {
                    const unsigned a0 = dwp[hf * 4 + 0], a1 = dwp[hf * 4 + 1];
                    const unsigned b0 = dwp[hf * 4 + 2], b1 = dwp[hf * 4 + 3];
                    const unsigned sa0 = (unsigned)__shfl_xor((int)a0, 32);
                    const unsigned sa1 = (unsigned)__shfl_xor((int)a1, 32);
                    const unsigned sb0 = (unsigned)__shfl_xor((int)b0, 32);
                    const unsigned sb1 = (unsigned)__shfl_xor((int)b1, 32);
                    i32x4 d;
                    d[0] = h ? (int)sb0 : (int)a0;
                    d[1] = h ? (int)sb1 : (int)a1;
                    d[2] = h ? (int)b0  : (int)sa0;
                    d[3] = h ? (int)b1  : (int)sa1;
                    pa[hf].i = d;
                }
            }
            // ---- PV
            #pragma unroll
            for (int dt = 0; dt < 4; ++dt) {
                const f16* vrow = &Vt[(dt * 32 + l31) * VTSTR + h * 8];
                const f16x8 vb0 = *(const f16x8*)(vrow + 0);
                const f16x8 vb1 = *(const f16x8*)(vrow + 16);
                acc[dt] = __builtin_amdgcn_mfma_f32_32x32x16_f16(pa[0].h, vb0, acc[dt], 0, 0, 0);
                acc[dt] = __builtin_amdgcn_mfma_f32_32x32x16_f16(pa[1].h, vb1, acc[dt], 0, 0, 0);
            }
        }
    }

    // ---- epilogue: O = acc / l  (row=(r&3)+8*(r>>2)+4h, col=dt*32+l31)
    float li[16];
    #pragma unroll
    for (int r = 0; r < 16; ++r) {
        const float lv = __shfl(l_i, (r & 3) + 8 * (r >> 2) + 4 * h);
        li[r] = 1.0f / lv;
    }
    #pragma unroll
    for (int dt = 0; dt < 4; ++dt)
        #pragma unroll
        for (int r = 0; r < 16; ++r) {
            const int row = qw0 + (r & 3) + 8 * (r >> 2) + 4 * h;
            Ob[(size_t)row * D_ + dt * 32 + l31] = acc[dt][r] * li[r];
        }
}

extern "C" void kernel_launch(void* const* d_in, const int* in_sizes, int n_in,
                              void* d_out, int out_size, void* d_ws, size_t ws_size,
                              hipStream_t stream) {
    (void)in_sizes; (void)n_in; (void)d_ws; (void)ws_size; (void)out_size;
    const float* Q = (const float*)d_in[0];
    const float* K = (const float*)d_in[1];
    const float* V = (const float*)d_in[2];
    float* O = (float*)d_out;
    fattn4<<<dim3((S_ / 128) * B_ * H_), dim3(256), 0, stream>>>(Q, K, V, O);
}

// Round 6
// 231.876 us; speedup vs baseline: 3.4129x; 1.0256x over previous
//
#include <hip/hip_runtime.h>

typedef _Float16 f16;
typedef _Float16 f16x8 __attribute__((ext_vector_type(8)));
typedef float    f32x16 __attribute__((ext_vector_type(16)));
typedef int      i32x4 __attribute__((ext_vector_type(4)));

#define B_ 4
#define H_ 16
#define S_ 2048
#define D_ 128
#define KVB 32
#define KSTR 136      // 272B = 17x16B slots, 17%8=1 -> min-aliasing b128
#define VTSTR 40      // 80B  =  5x16B slots,  5%8=5 -> min-aliasing b128

union U4 { i32x4 i; f16x8 h; };

__device__ __forceinline__ unsigned pk2(float a, float b) {
    auto v = __builtin_amdgcn_cvt_pkrtz(a, b);
    return __builtin_bit_cast(unsigned, v);
}

__global__ __launch_bounds__(256, 3)
void fattn5(const float* __restrict__ Qg, const float* __restrict__ Kg,
            const float* __restrict__ Vg, float* __restrict__ Og)
{
    __shared__ __align__(16) f16 Klds[2][KVB * KSTR];   // 2 x 8704 B
    __shared__ __align__(16) f16 Vt[2][128 * VTSTR];    // 2 x 10240 B  (37888 total)

    // XCD-clustered + LPT: qt descending in dispatch order, all 16 q-tiles of a bh on one XCD
    const int id  = blockIdx.x;
    const int xcd = id & 7;
    const int w   = id >> 3;
    const int qt  = 15 - (w & 15);       // big blocks dispatched first
    const int bh  = xcd + 8 * (w >> 4);

    const int tid  = threadIdx.x;
    const int lane = tid & 63;
    const int wv   = tid >> 6;
    const int l31  = lane & 31;
    const int h    = lane >> 5;

    const int qw0 = qt * 128 + wv * 32;
    const int qg  = qw0 + l31;

    const size_t base = (size_t)bh * S_ * D_;
    const float* Qb = Qg + base;
    const float* Kb = Kg + base;
    const float* Vb = Vg + base;
    float*       Ob = Og + base;

    const int nkt = 4 * qt + 4;

    // ---- landing regs for one in-flight KV tile
    float4 kr[4];
    float  vr[16];

    auto issue = [&](int kt) {
        const int k0n = kt * KVB;
        #pragma unroll
        for (int it = 0; it < 2; ++it) {
            const int idx  = tid + it * 256;        // 0..511
            const int krow = idx >> 4;              // 0..31
            const int c8   = idx & 15;
            const float* kp = Kb + (size_t)(k0n + krow) * D_ + c8 * 8;
            kr[it * 2]     = *(const float4*)kp;
            kr[it * 2 + 1] = *(const float4*)(kp + 4);
            const int d  = idx & 127;
            const int k8 = idx >> 7;                // 0..3
            const float* vp = Vb + (size_t)(k0n + k8 * 8) * D_ + d;
            #pragma unroll
            for (int e = 0; e < 8; ++e) vr[it * 8 + e] = vp[(size_t)e * D_];
        }
    };
    auto writeLds = [&](int buf) {
        #pragma unroll
        for (int it = 0; it < 2; ++it) {
            const int idx  = tid + it * 256;
            const int krow = idx >> 4;
            const int c8   = idx & 15;
            const float4 ka  = kr[it * 2];
            const float4 kb4 = kr[it * 2 + 1];
            f16x8 kh;
            kh[0] = (f16)ka.x;  kh[1] = (f16)ka.y;  kh[2] = (f16)ka.z;  kh[3] = (f16)ka.w;
            kh[4] = (f16)kb4.x; kh[5] = (f16)kb4.y; kh[6] = (f16)kb4.z; kh[7] = (f16)kb4.w;
            *(f16x8*)&Klds[buf][krow * KSTR + c8 * 8] = kh;
            const int d  = idx & 127;
            const int k8 = idx >> 7;
            f16x8 vh;
            #pragma unroll
            for (int e = 0; e < 8; ++e) vh[e] = (f16)vr[it * 8 + e];
            *(f16x8*)&Vt[buf][d * VTSTR + k8 * 8] = vh;
        }
    };

    // ---- Q fragments first (so kr/vr loads are the only outstanding VMEM later)
    const float qmul = 0.08838834764831845f * 1.4426950408889634f;
    f16x8 qf[8];
    {
        const float* Qrow = Qb + (size_t)(qw0 + l31) * D_;
        #pragma unroll
        for (int dc = 0; dc < 8; ++dc) {
            const float4 a = *(const float4*)(Qrow + dc * 16 + h * 8);
            const float4 b = *(const float4*)(Qrow + dc * 16 + h * 8 + 4);
            f16x8 q;
            q[0] = (f16)(a.x * qmul); q[1] = (f16)(a.y * qmul);
            q[2] = (f16)(a.z * qmul); q[3] = (f16)(a.w * qmul);
            q[4] = (f16)(b.x * qmul); q[5] = (f16)(b.y * qmul);
            q[6] = (f16)(b.z * qmul); q[7] = (f16)(b.w * qmul);
            qf[dc] = q;
        }
    }

    f32x16 acc[4];
    #pragma unroll
    for (int dt = 0; dt < 4; ++dt)
        #pragma unroll
        for (int r = 0; r < 16; ++r) acc[dt][r] = 0.f;
    float m_i = -1e30f, l_i = 0.f;

    // ---- pipeline prologue: buf0 <- tile0; tile1 loads in flight
    issue(0);
    writeLds(0);
    if (nkt > 1) issue(1);
    __syncthreads();

    for (int kt = 0; kt < nkt; ++kt) {
        const int k0  = kt * KVB;
        const int cur = kt & 1;

        if (k0 <= qw0 + 31) {
            // ---- swapped QK^T: S^T, lane: q=l31, k=(r&3)+8*(r>>2)+4h
            f32x16 sv;
            #pragma unroll
            for (int r = 0; r < 16; ++r) sv[r] = 0.f;
            __builtin_amdgcn_s_setprio(1);
            #pragma unroll
            for (int dc = 0; dc < 8; ++dc) {
                const f16x8 kf = *(const f16x8*)&Klds[cur][l31 * KSTR + dc * 16 + h * 8];
                sv = __builtin_amdgcn_mfma_f32_32x32x16_f16(kf, qf[dc], sv, 0, 0, 0);
            }
            __builtin_amdgcn_s_setprio(0);
            // ---- causal mask
            if (k0 + 31 > qw0) {
                #pragma unroll
                for (int r = 0; r < 16; ++r) {
                    const int kg = k0 + (r & 3) + 8 * (r >> 2) + 4 * h;
                    if (kg > qg) sv[r] = -1e30f;
                }
            }
            // ---- online softmax (row q=l31, split across lane^32)
            float mx = sv[0];
            #pragma unroll
            for (int r = 1; r < 16; ++r) mx = fmaxf(mx, sv[r]);
            mx = fmaxf(mx, __shfl_xor(mx, 32));
            if (!__all(mx - m_i <= 8.0f)) {       // defer-max (T13)
                const float mn = fmaxf(m_i, mx);
                const float al = exp2f(m_i - mn);
                m_i = mn;
                l_i *= al;
                float arow[16];
                #pragma unroll
                for (int r = 0; r < 16; ++r)
                    arow[r] = __shfl(al, (r & 3) + 8 * (r >> 2) + 4 * h);
                #pragma unroll
                for (int dt = 0; dt < 4; ++dt)
                    #pragma unroll
                    for (int r = 0; r < 16; ++r) acc[dt][r] *= arow[r];
            }
            float rs = 0.f;
            #pragma unroll
            for (int r = 0; r < 16; ++r) {
                sv[r] = exp2f(sv[r] - m_i);
                rs += sv[r];
            }
            rs += __shfl_xor(rs, 32);
            l_i += rs;
            // ---- P -> f16 A-frags (pack + cross-half exchange)
            U4 pa[2];
            {
                unsigned dwp[8];
                #pragma unroll
                for (int m = 0; m < 8; ++m) dwp[m] = pk2(sv[2 * m], sv[2 * m + 1]);
                #pragma unroll
                for (int hf = 0; hf < 2; ++hf) {
                    const unsigned a0 = dwp[hf * 4 + 0], a1 = dwp[hf * 4 + 1];
                    const unsigned b0 = dwp[hf * 4 + 2], b1 = dwp[hf * 4 + 3];
                    const unsigned sa0 = (unsigned)__shfl_xor((int)a0, 32);
                    const unsigned sa1 = (unsigned)__shfl_xor((int)a1, 32);
                    const unsigned sb0 = (unsigned)__shfl_xor((int)b0, 32);
                    const unsigned sb1 = (unsigned)__shfl_xor((int)b1, 32);
                    i32x4 d;
                    d[0] = h ? (int)sb0 : (int)a0;
                    d[1] = h ? (int)sb1 : (int)a1;
                    d[2] = h ? (int)b0  : (int)sa0;
                    d[3] = h ? (int)b1  : (int)sa1;
                    pa[hf].i = d;
                }
            }
            // ---- PV
            __builtin_amdgcn_s_setprio(1);
            #pragma unroll
            for (int dt = 0; dt < 4; ++dt) {
                const f16* vrow = &Vt[cur][(dt * 32 + l31) * VTSTR + h * 8];
                const f16x8 vb0 = *(const f16x8*)(vrow + 0);
                const f16x8 vb1 = *(const f16x8*)(vrow + 16);
                acc[dt] = __builtin_amdgcn_mfma_f32_32x32x16_f16(pa[0].h, vb0, acc[dt], 0, 0, 0);
                acc[dt] = __builtin_amdgcn_mfma_f32_32x32x16_f16(pa[1].h, vb1, acc[dt], 0, 0, 0);
            }
            __builtin_amdgcn_s_setprio(0);
        }

        if (kt + 1 < nkt) {
            // tile kt+1's loads have been in flight during compute; land them into buf^1
            writeLds(cur ^ 1);
            if (kt + 2 < nkt) issue(kt + 2);
            __syncthreads();        // single barrier per tile
        }
    }

    // ---- epilogue: O = acc / l  (row=(r&3)+8*(r>>2)+4h, col=dt*32+l31)
    float li[16];
    #pragma unroll
    for (int r = 0; r < 16; ++r) {
        const float lv = __shfl(l_i, (r & 3) + 8 * (r >> 2) + 4 * h);
        li[r] = 1.0f / lv;
    }
    #pragma unroll
    for (int dt = 0; dt < 4; ++dt)
        #pragma unroll
        for (int r = 0; r < 16; ++r) {
            const int row = qw0 + (r & 3) + 8 * (r >> 2) + 4 * h;
            Ob[(size_t)row * D_ + dt * 32 + l31] = acc[dt][r] * li[r];
        }
}

extern "C" void kernel_launch(void* const* d_in, const int* in_sizes, int n_in,
                              void* d_out, int out_size, void* d_ws, size_t ws_size,
                              hipStream_t stream) {
    (void)in_sizes; (void)n_in; (void)d_ws; (void)ws_size; (void)out_size;
    const float* Q = (const float*)d_in[0];
    const float* K = (const float*)d_in[1];
    const float* V = (const float*)d_in[2];
    float* O = (float*)d_out;
    fattn5<<<dim3((S_ / 128) * B_ * H_), dim3(256), 0, stream>>>(Q, K, V, O);
}

// Round 7
// 198.209 us; speedup vs baseline: 3.9927x; 1.1699x over previous
//
#include <hip/hip_runtime.h>

typedef _Float16 f16;
typedef _Float16 f16x8 __attribute__((ext_vector_type(8)));
typedef float    f32x16 __attribute__((ext_vector_type(16)));
typedef int      i32x4 __attribute__((ext_vector_type(4)));

#define B_ 4
#define H_ 16
#define S_ 2048
#define D_ 128
#define KVB 32
#define KSTR 136      // 272B = 17x16B slots, 17%8=1 -> min-aliasing b128
#define VTSTR 40      // 80B  =  5x16B slots,  5%8=5 -> min-aliasing b128

union U4 { i32x4 i; f16x8 h; };

__device__ __forceinline__ unsigned pk2(float a, float b) {
    auto v = __builtin_amdgcn_cvt_pkrtz(a, b);
    return __builtin_bit_cast(unsigned, v);
}

__device__ __forceinline__ f16x8 cvt8(const float4 a, const float4 b) {
    f16x8 h;
    h[0] = (f16)a.x; h[1] = (f16)a.y; h[2] = (f16)a.z; h[3] = (f16)a.w;
    h[4] = (f16)b.x; h[5] = (f16)b.y; h[6] = (f16)b.z; h[7] = (f16)b.w;
    return h;
}

// ---------------- pre-pass: K -> f16 row-major; V -> f16 tile-transposed ----------------
// Vtt layout: [bh][kt = k/32][d][kk = k%32]  (one 32-key tile = contiguous 8KB)
__global__ __launch_bounds__(256)
void prep(const float* __restrict__ K, const float* __restrict__ V,
          f16* __restrict__ Kh, f16* __restrict__ Vtt)
{
    const int bid = blockIdx.x;          // 0 .. 64*32-1
    const int bh  = bid >> 5;
    const int kb  = bid & 31;            // 64-key chunk
    const int k0  = kb * 64;
    const int tid = threadIdx.x;

    const float* Kb = K + ((size_t)bh * S_ + k0) * D_;
    const float* Vb = V + ((size_t)bh * S_ + k0) * D_;
    f16* Khb = Kh + ((size_t)bh * S_ + k0) * D_;
    f16* Vtb = Vtt + (size_t)bh * S_ * D_ + (size_t)kb * 2 * (D_ * 32);

    #pragma unroll
    for (int it = 0; it < 4; ++it) {
        const int idx = tid + it * 256;          // 0..1023
        const int row = idx >> 4, c8 = idx & 15;
        const float4 a = *(const float4*)(Kb + row * D_ + c8 * 8);
        const float4 b = *(const float4*)(Kb + row * D_ + c8 * 8 + 4);
        *(f16x8*)(Khb + row * D_ + c8 * 8) = cvt8(a, b);
    }
    #pragma unroll
    for (int it = 0; it < 4; ++it) {
        const int idx = tid + it * 256;          // 0..1023
        const int d  = idx & 127;
        const int k8 = idx >> 7;                 // 0..7
        const float* vp = Vb + (size_t)(k8 * 8) * D_ + d;
        f16x8 vh;
        #pragma unroll
        for (int e = 0; e < 8; ++e) vh[e] = (f16)vp[(size_t)e * D_];
        *(f16x8*)(Vtb + (size_t)(k8 >> 2) * (D_ * 32) + d * 32 + (k8 & 3) * 8) = vh;
    }
}

// ---------------- main kernel: f16 K/V from workspace ----------------
__global__ __launch_bounds__(256, 3)
void fattn6(const float* __restrict__ Qg, const f16* __restrict__ Khg,
            const f16* __restrict__ Vttg, float* __restrict__ Og)
{
    __shared__ __align__(16) f16 Klds[2][KVB * KSTR];
    __shared__ __align__(16) f16 Vt[2][128 * VTSTR];

    const int id  = blockIdx.x;
    const int xcd = id & 7;
    const int w   = id >> 3;
    const int qt  = 15 - (w & 15);       // LPT: big blocks first
    const int bh  = xcd + 8 * (w >> 4);

    const int tid  = threadIdx.x;
    const int lane = tid & 63;
    const int l31  = lane & 31;
    const int h    = lane >> 5;
    const int wv   = tid >> 6;

    const int qw0 = qt * 128 + wv * 32;
    const int qg  = qw0 + l31;

    const float* Qb  = Qg  + (size_t)bh * S_ * D_;
    const f16*   Khb = Khg + (size_t)bh * S_ * D_;
    const f16*   Vtb = Vttg + (size_t)bh * S_ * D_;
    float*       Ob  = Og  + (size_t)bh * S_ * D_;

    const int nkt = 4 * qt + 4;

    i32x4 kr[2], vr[2];
    auto issue = [&](int kt) {
        const int k0n = kt * KVB;
        #pragma unroll
        for (int it = 0; it < 2; ++it) {
            const int idx  = tid + it * 256;     // 0..511
            const int krow = idx >> 4, c8 = idx & 15;
            kr[it] = *(const i32x4*)(Khb + (size_t)(k0n + krow) * D_ + c8 * 8);
            vr[it] = *(const i32x4*)(Vtb + (size_t)kt * (D_ * 32) + (size_t)idx * 8);
        }
    };
    auto writeLds = [&](int buf) {
        #pragma unroll
        for (int it = 0; it < 2; ++it) {
            const int idx  = tid + it * 256;
            const int krow = idx >> 4, c8 = idx & 15;
            *(i32x4*)&Klds[buf][krow * KSTR + c8 * 8] = kr[it];
            const int d = idx >> 2, kk8 = idx & 3;
            *(i32x4*)&Vt[buf][d * VTSTR + kk8 * 8] = vr[it];
        }
    };

    // ---- Q fragments (B-operand: col=q=l31, k-dim d = dc*16 + 8h + j), pre-scaled
    const float qmul = 0.08838834764831845f * 1.4426950408889634f;
    f16x8 qf[8];
    {
        const float* Qrow = Qb + (size_t)(qw0 + l31) * D_;
        #pragma unroll
        for (int dc = 0; dc < 8; ++dc) {
            const float4 a = *(const float4*)(Qrow + dc * 16 + h * 8);
            const float4 b = *(const float4*)(Qrow + dc * 16 + h * 8 + 4);
            f16x8 q;
            q[0] = (f16)(a.x * qmul); q[1] = (f16)(a.y * qmul);
            q[2] = (f16)(a.z * qmul); q[3] = (f16)(a.w * qmul);
            q[4] = (f16)(b.x * qmul); q[5] = (f16)(b.y * qmul);
            q[6] = (f16)(b.z * qmul); q[7] = (f16)(b.w * qmul);
            qf[dc] = q;
        }
    }

    f32x16 acc[4];
    #pragma unroll
    for (int dt = 0; dt < 4; ++dt)
        #pragma unroll
        for (int r = 0; r < 16; ++r) acc[dt][r] = 0.f;
    float m_i = -1e30f, l_i = 0.f;

    issue(0);
    writeLds(0);
    if (nkt > 1) issue(1);
    __syncthreads();

    for (int kt = 0; kt < nkt; ++kt) {
        const int k0  = kt * KVB;
        const int cur = kt & 1;

        if (k0 <= qw0 + 31) {
            f32x16 sv;
            #pragma unroll
            for (int r = 0; r < 16; ++r) sv[r] = 0.f;
            __builtin_amdgcn_s_setprio(1);
            #pragma unroll
            for (int dc = 0; dc < 8; ++dc) {
                const f16x8 kf = *(const f16x8*)&Klds[cur][l31 * KSTR + dc * 16 + h * 8];
                sv = __builtin_amdgcn_mfma_f32_32x32x16_f16(kf, qf[dc], sv, 0, 0, 0);
            }
            __builtin_amdgcn_s_setprio(0);
            if (k0 + 31 > qw0) {
                #pragma unroll
                for (int r = 0; r < 16; ++r) {
                    const int kg = k0 + (r & 3) + 8 * (r >> 2) + 4 * h;
                    if (kg > qg) sv[r] = -1e30f;
                }
            }
            float mx = sv[0];
            #pragma unroll
            for (int r = 1; r < 16; ++r) mx = fmaxf(mx, sv[r]);
            mx = fmaxf(mx, __shfl_xor(mx, 32));
            if (!__all(mx - m_i <= 8.0f)) {       // defer-max (T13)
                const float mn = fmaxf(m_i, mx);
                const float al = exp2f(m_i - mn);
                m_i = mn;
                l_i *= al;
                float arow[16];
                #pragma unroll
                for (int r = 0; r < 16; ++r)
                    arow[r] = __shfl(al, (r & 3) + 8 * (r >> 2) + 4 * h);
                #pragma unroll
                for (int dt = 0; dt < 4; ++dt)
                    #pragma unroll
                    for (int r = 0; r < 16; ++r) acc[dt][r] *= arow[r];
            }
            float rs = 0.f;
            #pragma unroll
            for (int r = 0; r < 16; ++r) {
                sv[r] = exp2f(sv[r] - m_i);
                rs += sv[r];
            }
            rs += __shfl_xor(rs, 32);
            l_i += rs;
            U4 pa[2];
            {
                unsigned dwp[8];
                #pragma unroll
                for (int m = 0; m < 8; ++m) dwp[m] = pk2(sv[2 * m], sv[2 * m + 1]);
                #pragma unroll
                for (int hf = 0; hf < 2; ++hf) {
                    const unsigned a0 = dwp[hf * 4 + 0], a1 = dwp[hf * 4 + 1];
                    const unsigned b0 = dwp[hf * 4 + 2], b1 = dwp[hf * 4 + 3];
                    const unsigned sa0 = (unsigned)__shfl_xor((int)a0, 32);
                    const unsigned sa1 = (unsigned)__shfl_xor((int)a1, 32);
                    const unsigned sb0 = (unsigned)__shfl_xor((int)b0, 32);
                    const unsigned sb1 = (unsigned)__shfl_xor((int)b1, 32);
                    i32x4 d;
                    d[0] = h ? (int)sb0 : (int)a0;
                    d[1] = h ? (int)sb1 : (int)a1;
                    d[2] = h ? (int)b0  : (int)sa0;
                    d[3] = h ? (int)b1  : (int)sa1;
                    pa[hf].i = d;
                }
            }
            __builtin_amdgcn_s_setprio(1);
            #pragma unroll
            for (int dt = 0; dt < 4; ++dt) {
                const f16* vrow = &Vt[cur][(dt * 32 + l31) * VTSTR + h * 8];
                const f16x8 vb0 = *(const f16x8*)(vrow + 0);
                const f16x8 vb1 = *(const f16x8*)(vrow + 16);
                acc[dt] = __builtin_amdgcn_mfma_f32_32x32x16_f16(pa[0].h, vb0, acc[dt], 0, 0, 0);
                acc[dt] = __builtin_amdgcn_mfma_f32_32x32x16_f16(pa[1].h, vb1, acc[dt], 0, 0, 0);
            }
            __builtin_amdgcn_s_setprio(0);
        }

        if (kt + 1 < nkt) {
            writeLds(cur ^ 1);
            if (kt + 2 < nkt) issue(kt + 2);
            __syncthreads();
        }
    }

    float li[16];
    #pragma unroll
    for (int r = 0; r < 16; ++r) {
        const float lv = __shfl(l_i, (r & 3) + 8 * (r >> 2) + 4 * h);
        li[r] = 1.0f / lv;
    }
    #pragma unroll
    for (int dt = 0; dt < 4; ++dt)
        #pragma unroll
        for (int r = 0; r < 16; ++r) {
            const int row = qw0 + (r & 3) + 8 * (r >> 2) + 4 * h;
            Ob[(size_t)row * D_ + dt * 32 + l31] = acc[dt][r] * li[r];
        }
}

// ---------------- fallback (ws too small): round-5 kernel, f32 in-loop staging ----------------
__global__ __launch_bounds__(256, 3)
void fattn5(const float* __restrict__ Qg, const float* __restrict__ Kg,
            const float* __restrict__ Vg, float* __restrict__ Og)
{
    __shared__ __align__(16) f16 Klds[2][KVB * KSTR];
    __shared__ __align__(16) f16 Vt[2][128 * VTSTR];
    const int id  = blockIdx.x;
    const int xcd = id & 7;
    const int w   = id >> 3;
    const int qt  = 15 - (w & 15);
    const int bh  = xcd + 8 * (w >> 4);
    const int tid  = threadIdx.x;
    const int lane = tid & 63;
    const int wv   = tid >> 6;
    const int l31  = lane & 31;
    const int h    = lane >> 5;
    const int qw0 = qt * 128 + wv * 32;
    const int qg  = qw0 + l31;
    const size_t base = (size_t)bh * S_ * D_;
    const float* Qb = Qg + base;
    const float* Kb = Kg + base;
    const float* Vb = Vg + base;
    float*       Ob = Og + base;
    const int nkt = 4 * qt + 4;
    float4 kr[4];
    float  vr[16];
    auto issue = [&](int kt) {
        const int k0n = kt * KVB;
        #pragma unroll
        for (int it = 0; it < 2; ++it) {
            const int idx  = tid + it * 256;
            const int krow = idx >> 4;
            const int c8   = idx & 15;
            const float* kp = Kb + (size_t)(k0n + krow) * D_ + c8 * 8;
            kr[it * 2]     = *(const float4*)kp;
            kr[it * 2 + 1] = *(const float4*)(kp + 4);
            const int d  = idx & 127;
            const int k8 = idx >> 7;
            const float* vp = Vb + (size_t)(k0n + k8 * 8) * D_ + d;
            #pragma unroll
            for (int e = 0; e < 8; ++e) vr[it * 8 + e] = vp[(size_t)e * D_];
        }
    };
    auto writeLds = [&](int buf) {
        #pragma unroll
        for (int it = 0; it < 2; ++it) {
            const int idx  = tid + it * 256;
            const int krow = idx >> 4;
            const int c8   = idx & 15;
            *(f16x8*)&Klds[buf][krow * KSTR + c8 * 8] = cvt8(kr[it * 2], kr[it * 2 + 1]);
            const int d  = idx & 127;
            const int k8 = idx >> 7;
            f16x8 vh;
            #pragma unroll
            for (int e = 0; e < 8; ++e) vh[e] = (f16)vr[it * 8 + e];
            *(f16x8*)&Vt[buf][d * VTSTR + k8 * 8] = vh;
        }
    };
    const float qmul = 0.08838834764831845f * 1.4426950408889634f;
    f16x8 qf[8];
    {
        const float* Qrow = Qb + (size_t)(qw0 + l31) * D_;
        #pragma unroll
        for (int dc = 0; dc < 8; ++dc) {
            const float4 a = *(const float4*)(Qrow + dc * 16 + h * 8);
            const float4 b = *(const float4*)(Qrow + dc * 16 + h * 8 + 4);
            f16x8 q;
            q[0] = (f16)(a.x * qmul); q[1] = (f16)(a.y * qmul);
            q[2] = (f16)(a.z * qmul); q[3] = (f16)(a.w * qmul);
            q[4] = (f16)(b.x * qmul); q[5] = (f16)(b.y * qmul);
            q[6] = (f16)(b.z * qmul); q[7] = (f16)(b.w * qmul);
            qf[dc] = q;
        }
    }
    f32x16 acc[4];
    #pragma unroll
    for (int dt = 0; dt < 4; ++dt)
        #pragma unroll
        for (int r = 0; r < 16; ++r) acc[dt][r] = 0.f;
    float m_i = -1e30f, l_i = 0.f;
    issue(0);
    writeLds(0);
    if (nkt > 1) issue(1);
    __syncthreads();
    for (int kt = 0; kt < nkt; ++kt) {
        const int k0  = kt * KVB;
        const int cur = kt & 1;
        if (k0 <= qw0 + 31) {
            f32x16 sv;
            #pragma unroll
            for (int r = 0; r < 16; ++r) sv[r] = 0.f;
            #pragma unroll
            for (int dc = 0; dc < 8; ++dc) {
                const f16x8 kf = *(const f16x8*)&Klds[cur][l31 * KSTR + dc * 16 + h * 8];
                sv = __builtin_amdgcn_mfma_f32_32x32x16_f16(kf, qf[dc], sv, 0, 0, 0);
            }
            if (k0 + 31 > qw0) {
                #pragma unroll
                for (int r = 0; r < 16; ++r) {
                    const int kg = k0 + (r & 3) + 8 * (r >> 2) + 4 * h;
                    if (kg > qg) sv[r] = -1e30f;
                }
            }
            float mx = sv[0];
            #pragma unroll
            for (int r = 1; r < 16; ++r) mx = fmaxf(mx, sv[r]);
            mx = fmaxf(mx, __shfl_xor(mx, 32));
            if (!__all(mx - m_i <= 8.0f)) {
                const float mn = fmaxf(m_i, mx);
                const float al = exp2f(m_i - mn);
                m_i = mn;
                l_i *= al;
                float arow[16];
                #pragma unroll
                for (int r = 0; r < 16; ++r)
                    arow[r] = __shfl(al, (r & 3) + 8 * (r >> 2) + 4 * h);
                #pragma unroll
                for (int dt = 0; dt < 4; ++dt)
                    #pragma unroll
                    for (int r = 0; r < 16; ++r) acc[dt][r] *= arow[r];
            }
            float rs = 0.f;
            #pragma unroll
            for (int r = 0; r < 16; ++r) {
                sv[r] = exp2f(sv[r] - m_i);
                rs += sv[r];
            }
            rs += __shfl_xor(rs, 32);
            l_i += rs;
            U4 pa[2];
            {
                unsigned dwp[8];
                #pragma unroll
                for (int m = 0; m < 8; ++m) dwp[m] = pk2(sv[2 * m], sv[2 * m + 1]);
                #pragma unroll
                for (int hf = 0; hf < 2; ++hf) {
                    const unsigned a0 = dwp[hf * 4 + 0], a1 = dwp[hf * 4 + 1];
                    const unsigned b0 = dwp[hf * 4 + 2], b1 = dwp[hf * 4 + 3];
                    const unsigned sa0 = (unsigned)__shfl_xor((int)a0, 32);
                    const unsigned sa1 = (unsigned)__shfl_xor((int)a1, 32);
                    const unsigned sb0 = (unsigned)__shfl_xor((int)b0, 32);
                    const unsigned sb1 = (unsigned)__shfl_xor((int)b1, 32);
                    i32x4 d;
                    d[0] = h ? (int)sb0 : (int)a0;
                    d[1] = h ? (int)sb1 : (int)a1;
                    d[2] = h ? (int)b0  : (int)sa0;
                    d[3] = h ? (int)b1  : (int)sa1;
                    pa[hf].i = d;
                }
            }
            #pragma unroll
            for (int dt = 0; dt < 4; ++dt) {
                const f16* vrow = &Vt[cur][(dt * 32 + l31) * VTSTR + h * 8];
                const f16x8 vb0 = *(const f16x8*)(vrow + 0);
                const f16x8 vb1 = *(const f16x8*)(vrow + 16);
                acc[dt] = __builtin_amdgcn_mfma_f32_32x32x16_f16(pa[0].h, vb0, acc[dt], 0, 0, 0);
                acc[dt] = __builtin_amdgcn_mfma_f32_32x32x16_f16(pa[1].h, vb1, acc[dt], 0, 0, 0);
            }
        }
        if (kt + 1 < nkt) {
            writeLds(cur ^ 1);
            if (kt + 2 < nkt) issue(kt + 2);
            __syncthreads();
        }
    }
    float li[16];
    #pragma unroll
    for (int r = 0; r < 16; ++r) {
        const float lv = __shfl(l_i, (r & 3) + 8 * (r >> 2) + 4 * h);
        li[r] = 1.0f / lv;
    }
    #pragma unroll
    for (int dt = 0; dt < 4; ++dt)
        #pragma unroll
        for (int r = 0; r < 16; ++r) {
            const int row = qw0 + (r & 3) + 8 * (r >> 2) + 4 * h;
            Ob[(size_t)row * D_ + dt * 32 + l31] = acc[dt][r] * li[r];
        }
}

extern "C" void kernel_launch(void* const* d_in, const int* in_sizes, int n_in,
                              void* d_out, int out_size, void* d_ws, size_t ws_size,
                              hipStream_t stream) {
    (void)in_sizes; (void)n_in; (void)out_size;
    const float* Q = (const float*)d_in[0];
    const float* K = (const float*)d_in[1];
    const float* V = (const float*)d_in[2];
    float* O = (float*)d_out;
    const size_t elems = (size_t)B_ * H_ * S_ * D_;
    const size_t need  = elems * 2 * sizeof(f16);     // Kh + Vtt
    if (ws_size >= need) {
        f16* Kh  = (f16*)d_ws;
        f16* Vtt = Kh + elems;
        prep<<<dim3(B_ * H_ * (S_ / 64)), dim3(256), 0, stream>>>(K, V, Kh, Vtt);
        fattn6<<<dim3((S_ / 128) * B_ * H_), dim3(256), 0, stream>>>(Q, Kh, Vtt, O);
    } else {
        fattn5<<<dim3((S_ / 128) * B_ * H_), dim3(256), 0, stream>>>(Q, K, V, O);
    }
}

// Round 8
// 186.023 us; speedup vs baseline: 4.2542x; 1.0655x over previous
//
#include <hip/hip_runtime.h>

typedef _Float16 f16;
typedef _Float16 f16x4 __attribute__((ext_vector_type(4)));
typedef _Float16 f16x8 __attribute__((ext_vector_type(8)));
typedef float    f32x16 __attribute__((ext_vector_type(16)));
typedef int      i32x4 __attribute__((ext_vector_type(4)));

#define B_ 4
#define H_ 16
#define S_ 2048
#define D_ 128
#define KVB 32
#define KSTR 136      // 272B = 17x16B slots, 17%8=1 -> min-aliasing b128
#define VTSTR 40      // 80B  =  5x16B slots,  5%8=5 -> min-aliasing b128

union U4 { i32x4 i; f16x8 h; };

__device__ __forceinline__ unsigned pk2(float a, float b) {
    auto v = __builtin_amdgcn_cvt_pkrtz(a, b);
    return __builtin_bit_cast(unsigned, v);
}

__device__ __forceinline__ f16x8 cvt8(const float4 a, const float4 b) {
    f16x8 h;
    h[0] = (f16)a.x; h[1] = (f16)a.y; h[2] = (f16)a.z; h[3] = (f16)a.w;
    h[4] = (f16)b.x; h[5] = (f16)b.y; h[6] = (f16)b.z; h[7] = (f16)b.w;
    return h;
}

// ---------------- pre-pass: K -> f16 row-major; V -> f16 tile-transposed ----------------
// Vtt layout: [bh][kt=k/32][d][kk=k%32]  (one 32-key tile = contiguous 8KB)
__global__ __launch_bounds__(256)
void prep(const float* __restrict__ K, const float* __restrict__ V,
          f16* __restrict__ Kh, f16* __restrict__ Vtt)
{
    const int bid = blockIdx.x;
    const int bh  = bid >> 5;
    const int kb  = bid & 31;
    const int k0  = kb * 64;
    const int tid = threadIdx.x;

    const float* Kb = K + ((size_t)bh * S_ + k0) * D_;
    const float* Vb = V + ((size_t)bh * S_ + k0) * D_;
    f16* Khb = Kh + ((size_t)bh * S_ + k0) * D_;
    f16* Vtb = Vtt + (size_t)bh * S_ * D_ + (size_t)kb * 2 * (D_ * 32);

    #pragma unroll
    for (int it = 0; it < 4; ++it) {
        const int idx = tid + it * 256;
        const int row = idx >> 4, c8 = idx & 15;
        const float4 a = *(const float4*)(Kb + row * D_ + c8 * 8);
        const float4 b = *(const float4*)(Kb + row * D_ + c8 * 8 + 4);
        *(f16x8*)(Khb + row * D_ + c8 * 8) = cvt8(a, b);
    }
    #pragma unroll
    for (int it = 0; it < 4; ++it) {
        const int idx = tid + it * 256;
        const int d  = idx & 127;
        const int k8 = idx >> 7;
        const float* vp = Vb + (size_t)(k8 * 8) * D_ + d;
        f16x8 vh;
        #pragma unroll
        for (int e = 0; e < 8; ++e) vh[e] = (f16)vp[(size_t)e * D_];
        *(f16x8*)(Vtb + (size_t)(k8 >> 2) * (D_ * 32) + d * 32 + (k8 & 3) * 8) = vh;
    }
}

// ---------------- main kernel (templated: SPLIT writes f16 partials + ml) ----------------
template <bool SPLIT>
__global__ __launch_bounds__(256, 3)
void fattn7(const float* __restrict__ Qg, const f16* __restrict__ Khg,
            const f16* __restrict__ Vttg, float* __restrict__ Og,
            f16* __restrict__ Pg, float2* __restrict__ mlg)
{
    __shared__ __align__(16) f16 Klds[2][KVB * KSTR];
    __shared__ __align__(16) f16 Vt[2][128 * VTSTR];

    // XCD-clustered (all blocks of a bh on one XCD) + LPT (qt descending)
    const int id  = blockIdx.x;
    const int xcd = id & 7;
    int qt, s, bh;
    if (SPLIT) {
        const int r  = id >> 3;          // 0..255
        bh = xcd + 8 * (r & 7);
        const int rr = r >> 3;           // 0..31
        s  = rr & 1;
        qt = 15 - (rr >> 1);
    } else {
        const int w = id >> 3;
        qt = 15 - (w & 15);
        s  = 0;
        bh = xcd + 8 * (w >> 4);
    }

    const int tid  = threadIdx.x;
    const int lane = tid & 63;
    const int l31  = lane & 31;
    const int h    = lane >> 5;
    const int wv   = tid >> 6;

    const int qw0 = qt * 128 + wv * 32;
    const int qg  = qw0 + l31;

    const float* Qb  = Qg  + (size_t)bh * S_ * D_;
    const f16*   Khb = Khg + (size_t)bh * S_ * D_;
    const f16*   Vtb = Vttg + (size_t)bh * S_ * D_;

    const int nkt  = 4 * qt + 4;
    const int half = 2 * qt + 2;
    const int lo   = SPLIT ? (s ? half : 0) : 0;
    const int hi   = SPLIT ? (s ? nkt : half) : nkt;

    i32x4 kr[2], vr[2];
    auto issue = [&](int kt) {
        const int k0n = kt * KVB;
        #pragma unroll
        for (int it = 0; it < 2; ++it) {
            const int idx  = tid + it * 256;
            const int krow = idx >> 4, c8 = idx & 15;
            kr[it] = *(const i32x4*)(Khb + (size_t)(k0n + krow) * D_ + c8 * 8);
            vr[it] = *(const i32x4*)(Vtb + (size_t)kt * (D_ * 32) + (size_t)idx * 8);
        }
    };
    auto writeLds = [&](int buf) {
        #pragma unroll
        for (int it = 0; it < 2; ++it) {
            const int idx  = tid + it * 256;
            const int krow = idx >> 4, c8 = idx & 15;
            *(i32x4*)&Klds[buf][krow * KSTR + c8 * 8] = kr[it];
            const int d = idx >> 2, kk8 = idx & 3;
            *(i32x4*)&Vt[buf][d * VTSTR + kk8 * 8] = vr[it];
        }
    };

    // Q fragments (B-operand: col=q=l31, k-dim d = dc*16 + 8h + j), pre-scaled
    const float qmul = 0.08838834764831845f * 1.4426950408889634f;
    f16x8 qf[8];
    {
        const float* Qrow = Qb + (size_t)(qw0 + l31) * D_;
        #pragma unroll
        for (int dc = 0; dc < 8; ++dc) {
            const float4 a = *(const float4*)(Qrow + dc * 16 + h * 8);
            const float4 b = *(const float4*)(Qrow + dc * 16 + h * 8 + 4);
            f16x8 q;
            q[0] = (f16)(a.x * qmul); q[1] = (f16)(a.y * qmul);
            q[2] = (f16)(a.z * qmul); q[3] = (f16)(a.w * qmul);
            q[4] = (f16)(b.x * qmul); q[5] = (f16)(b.y * qmul);
            q[6] = (f16)(b.z * qmul); q[7] = (f16)(b.w * qmul);
            qf[dc] = q;
        }
    }

    f32x16 acc[4];
    #pragma unroll
    for (int dt = 0; dt < 4; ++dt)
        #pragma unroll
        for (int r = 0; r < 16; ++r) acc[dt][r] = 0.f;
    float m_i = -1e30f, l_i = 0.f;

    issue(lo);
    writeLds(0);
    if (lo + 1 < hi) issue(lo + 1);
    __syncthreads();

    for (int kt = lo; kt < hi; ++kt) {
        const int k0  = kt * KVB;
        const int cur = (kt - lo) & 1;

        if (k0 <= qw0 + 31) {
            f32x16 sv;
            #pragma unroll
            for (int r = 0; r < 16; ++r) sv[r] = 0.f;
            __builtin_amdgcn_s_setprio(1);
            #pragma unroll
            for (int dc = 0; dc < 8; ++dc) {
                const f16x8 kf = *(const f16x8*)&Klds[cur][l31 * KSTR + dc * 16 + h * 8];
                sv = __builtin_amdgcn_mfma_f32_32x32x16_f16(kf, qf[dc], sv, 0, 0, 0);
            }
            __builtin_amdgcn_s_setprio(0);
            if (k0 + 31 > qw0) {
                #pragma unroll
                for (int r = 0; r < 16; ++r) {
                    const int kg = k0 + (r & 3) + 8 * (r >> 2) + 4 * h;
                    if (kg > qg) sv[r] = -1e30f;
                }
            }
            float mx = sv[0];
            #pragma unroll
            for (int r = 1; r < 16; ++r) mx = fmaxf(mx, sv[r]);
            mx = fmaxf(mx, __shfl_xor(mx, 32));
            if (!__all(mx - m_i <= 8.0f)) {       // defer-max (T13)
                const float mn = fmaxf(m_i, mx);
                const float al = exp2f(m_i - mn);
                m_i = mn;
                l_i *= al;
                float arow[16];
                #pragma unroll
                for (int r = 0; r < 16; ++r)
                    arow[r] = __shfl(al, (r & 3) + 8 * (r >> 2) + 4 * h);
                #pragma unroll
                for (int dt = 0; dt < 4; ++dt)
                    #pragma unroll
                    for (int r = 0; r < 16; ++r) acc[dt][r] *= arow[r];
            }
            float rs = 0.f;
            #pragma unroll
            for (int r = 0; r < 16; ++r) {
                sv[r] = exp2f(sv[r] - m_i);
                rs += sv[r];
            }
            rs += __shfl_xor(rs, 32);
            l_i += rs;
            U4 pa[2];
            {
                unsigned dwp[8];
                #pragma unroll
                for (int m = 0; m < 8; ++m) dwp[m] = pk2(sv[2 * m], sv[2 * m + 1]);
                #pragma unroll
                for (int hf = 0; hf < 2; ++hf) {
                    const unsigned a0 = dwp[hf * 4 + 0], a1 = dwp[hf * 4 + 1];
                    const unsigned b0 = dwp[hf * 4 + 2], b1 = dwp[hf * 4 + 3];
                    const unsigned sa0 = (unsigned)__shfl_xor((int)a0, 32);
                    const unsigned sa1 = (unsigned)__shfl_xor((int)a1, 32);
                    const unsigned sb0 = (unsigned)__shfl_xor((int)b0, 32);
                    const unsigned sb1 = (unsigned)__shfl_xor((int)b1, 32);
                    i32x4 d;
                    d[0] = h ? (int)sb0 : (int)a0;
                    d[1] = h ? (int)sb1 : (int)a1;
                    d[2] = h ? (int)b0  : (int)sa0;
                    d[3] = h ? (int)b1  : (int)sa1;
                    pa[hf].i = d;
                }
            }
            __builtin_amdgcn_s_setprio(1);
            #pragma unroll
            for (int dt = 0; dt < 4; ++dt) {
                const f16* vrow = &Vt[cur][(dt * 32 + l31) * VTSTR + h * 8];
                const f16x8 vb0 = *(const f16x8*)(vrow + 0);
                const f16x8 vb1 = *(const f16x8*)(vrow + 16);
                acc[dt] = __builtin_amdgcn_mfma_f32_32x32x16_f16(pa[0].h, vb0, acc[dt], 0, 0, 0);
                acc[dt] = __builtin_amdgcn_mfma_f32_32x32x16_f16(pa[1].h, vb1, acc[dt], 0, 0, 0);
            }
            __builtin_amdgcn_s_setprio(0);
        }

        if (kt + 1 < hi) {
            writeLds(cur ^ 1);
            if (kt + 2 < hi) issue(kt + 2);
            __syncthreads();
        }
    }

    // epilogue (row=(r&3)+8*(r>>2)+4h, col=dt*32+l31)
    float li[16];
    #pragma unroll
    for (int r = 0; r < 16; ++r) {
        const float lv = __shfl(l_i, (r & 3) + 8 * (r >> 2) + 4 * h);
        li[r] = (lv > 0.f) ? 1.0f / lv : 0.f;
    }
    if (SPLIT) {
        f16* Pb = Pg + ((size_t)s * (B_ * H_) + bh) * (S_ * D_);
        #pragma unroll
        for (int dt = 0; dt < 4; ++dt)
            #pragma unroll
            for (int r = 0; r < 16; ++r) {
                const int row = qw0 + (r & 3) + 8 * (r >> 2) + 4 * h;
                Pb[(size_t)row * D_ + dt * 32 + l31] = (f16)(acc[dt][r] * li[r]);
            }
        if (h == 0)
            mlg[((size_t)s * (B_ * H_) + bh) * S_ + qw0 + l31] = make_float2(m_i, l_i);
    } else {
        float* Ob = Og + (size_t)bh * S_ * D_;
        #pragma unroll
        for (int dt = 0; dt < 4; ++dt)
            #pragma unroll
            for (int r = 0; r < 16; ++r) {
                const int row = qw0 + (r & 3) + 8 * (r >> 2) + 4 * h;
                Ob[(size_t)row * D_ + dt * 32 + l31] = acc[dt][r] * li[r];
            }
    }
}

// ---------------- merge: O = w0*P0 + w1*P1 ----------------
__global__ __launch_bounds__(256)
void merge(const f16* __restrict__ Pg, const float2* __restrict__ mlg,
           float* __restrict__ O)
{
    const size_t NROW   = (size_t)B_ * H_ * S_;
    const size_t total4 = NROW * (D_ / 4);
    const size_t stride = (size_t)gridDim.x * 256;
    for (size_t i = (size_t)blockIdx.x * 256 + threadIdx.x; i < total4; i += stride) {
        const size_t row = i >> 5;            // D/4 = 32
        const float2 a = mlg[row];
        const float2 b = mlg[NROW + row];
        const float ms = fmaxf(a.x, b.x);
        float w0 = exp2f(a.x - ms) * a.y;
        float w1 = exp2f(b.x - ms) * b.y;
        const float inv = 1.0f / (w0 + w1);
        w0 *= inv; w1 *= inv;
        const f16x4 p0 = *(const f16x4*)(Pg + i * 4);
        const f16x4 p1 = *(const f16x4*)(Pg + NROW * D_ + i * 4);
        float4 o;
        o.x = w0 * (float)p0[0] + w1 * (float)p1[0];
        o.y = w0 * (float)p0[1] + w1 * (float)p1[1];
        o.z = w0 * (float)p0[2] + w1 * (float)p1[2];
        o.w = w0 * (float)p0[3] + w1 * (float)p1[3];
        *(float4*)(O + i * 4) = o;
    }
}

// ---------------- fallback (tiny ws): f32 in-loop staging, single pass ----------------
__global__ __launch_bounds__(256, 3)
void fattn5(const float* __restrict__ Qg, const float* __restrict__ Kg,
            const float* __restrict__ Vg, float* __restrict__ Og)
{
    __shared__ __align__(16) f16 Klds[2][KVB * KSTR];
    __shared__ __align__(16) f16 Vt[2][128 * VTSTR];
    const int id  = blockIdx.x;
    const int xcd = id & 7;
    const int w   = id >> 3;
    const int qt  = 15 - (w & 15);
    const int bh  = xcd + 8 * (w >> 4);
    const int tid  = threadIdx.x;
    const int lane = tid & 63;
    const int wv   = tid >> 6;
    const int l31  = lane & 31;
    const int h    = lane >> 5;
    const int qw0 = qt * 128 + wv * 32;
    const int qg  = qw0 + l31;
    const size_t base = (size_t)bh * S_ * D_;
    const float* Qb = Qg + base;
    const float* Kb = Kg + base;
    const float* Vb = Vg + base;
    float*       Ob = Og + base;
    const int nkt = 4 * qt + 4;
    float4 kr[4];
    float  vr[16];
    auto issue = [&](int kt) {
        const int k0n = kt * KVB;
        #pragma unroll
        for (int it = 0; it < 2; ++it) {
            const int idx  = tid + it * 256;
            const int krow = idx >> 4;
            const int c8   = idx & 15;
            const float* kp = Kb + (size_t)(k0n + krow) * D_ + c8 * 8;
            kr[it * 2]     = *(const float4*)kp;
            kr[it * 2 + 1] = *(const float4*)(kp + 4);
            const int d  = idx & 127;
            const int k8 = idx >> 7;
            const float* vp = Vb + (size_t)(k0n + k8 * 8) * D_ + d;
            #pragma unroll
            for (int e = 0; e < 8; ++e) vr[it * 8 + e] = vp[(size_t)e * D_];
        }
    };
    auto writeLds = [&](int buf) {
        #pragma unroll
        for (int it = 0; it < 2; ++it) {
            const int idx  = tid + it * 256;
            const int krow = idx >> 4;
            const int c8   = idx & 15;
            *(f16x8*)&Klds[buf][krow * KSTR + c8 * 8] = cvt8(kr[it * 2], kr[it * 2 + 1]);
            const int d  = idx & 127;
            const int k8 = idx >> 7;
            f16x8 vh;
            #pragma unroll
            for (int e = 0; e < 8; ++e) vh[e] = (f16)vr[it * 8 + e];
            *(f16x8*)&Vt[buf][d * VTSTR + k8 * 8] = vh;
        }
    };
    const float qmul = 0.08838834764831845f * 1.4426950408889634f;
    f16x8 qf[8];
    {
        const float* Qrow = Qb + (size_t)(qw0 + l31) * D_;
        #pragma unroll
        for (int dc = 0; dc < 8; ++dc) {
            const float4 a = *(const float4*)(Qrow + dc * 16 + h * 8);
            const float4 b = *(const float4*)(Qrow + dc * 16 + h * 8 + 4);
            f16x8 q;
            q[0] = (f16)(a.x * qmul); q[1] = (f16)(a.y * qmul);
            q[2] = (f16)(a.z * qmul); q[3] = (f16)(a.w * qmul);
            q[4] = (f16)(b.x * qmul); q[5] = (f16)(b.y * qmul);
            q[6] = (f16)(b.z * qmul); q[7] = (f16)(b.w * qmul);
            qf[dc] = q;
        }
    }
    f32x16 acc[4];
    #pragma unroll
    for (int dt = 0; dt < 4; ++dt)
        #pragma unroll
        for (int r = 0; r < 16; ++r) acc[dt][r] = 0.f;
    float m_i = -1e30f, l_i = 0.f;
    issue(0);
    writeLds(0);
    if (nkt > 1) issue(1);
    __syncthreads();
    for (int kt = 0; kt < nkt; ++kt) {
        const int k0  = kt * KVB;
        const int cur = kt & 1;
        if (k0 <= qw0 + 31) {
            f32x16 sv;
            #pragma unroll
            for (int r = 0; r < 16; ++r) sv[r] = 0.f;
            #pragma unroll
            for (int dc = 0; dc < 8; ++dc) {
                const f16x8 kf = *(const f16x8*)&Klds[cur][l31 * KSTR + dc * 16 + h * 8];
                sv = __builtin_amdgcn_mfma_f32_32x32x16_f16(kf, qf[dc], sv, 0, 0, 0);
            }
            if (k0 + 31 > qw0) {
                #pragma unroll
                for (int r = 0; r < 16; ++r) {
                    const int kg = k0 + (r & 3) + 8 * (r >> 2) + 4 * h;
                    if (kg > qg) sv[r] = -1e30f;
                }
            }
            float mx = sv[0];
            #pragma unroll
            for (int r = 1; r < 16; ++r) mx = fmaxf(mx, sv[r]);
            mx = fmaxf(mx, __shfl_xor(mx, 32));
            if (!__all(mx - m_i <= 8.0f)) {
                const float mn = fmaxf(m_i, mx);
                const float al = exp2f(m_i - mn);
                m_i = mn;
                l_i *= al;
                float arow[16];
                #pragma unroll
                for (int r = 0; r < 16; ++r)
                    arow[r] = __shfl(al, (r & 3) + 8 * (r >> 2) + 4 * h);
                #pragma unroll
                for (int dt = 0; dt < 4; ++dt)
                    #pragma unroll
                    for (int r = 0; r < 16; ++r) acc[dt][r] *= arow[r];
            }
            float rs = 0.f;
            #pragma unroll
            for (int r = 0; r < 16; ++r) {
                sv[r] = exp2f(sv[r] - m_i);
                rs += sv[r];
            }
            rs += __shfl_xor(rs, 32);
            l_i += rs;
            U4 pa[2];
            {
                unsigned dwp[8];
                #pragma unroll
                for (int m = 0; m < 8; ++m) dwp[m] = pk2(sv[2 * m], sv[2 * m + 1]);
                #pragma unroll
                for (int hf = 0; hf < 2; ++hf) {
                    const unsigned a0 = dwp[hf * 4 + 0], a1 = dwp[hf * 4 + 1];
                    const unsigned b0 = dwp[hf * 4 + 2], b1 = dwp[hf * 4 + 3];
                    const unsigned sa0 = (unsigned)__shfl_xor((int)a0, 32);
                    const unsigned sa1 = (unsigned)__shfl_xor((int)a1, 32);
                    const unsigned sb0 = (unsigned)__shfl_xor((int)b0, 32);
                    const unsigned sb1 = (unsigned)__shfl_xor((int)b1, 32);
                    i32x4 d;
                    d[0] = h ? (int)sb0 : (int)a0;
                    d[1] = h ? (int)sb1 : (int)a1;
                    d[2] = h ? (int)b0  : (int)sa0;
                    d[3] = h ? (int)b1  : (int)sa1;
                    pa[hf].i = d;
                }
            }
            #pragma unroll
            for (int dt = 0; dt < 4; ++dt) {
                const f16* vrow = &Vt[cur][(dt * 32 + l31) * VTSTR + h * 8];
                const f16x8 vb0 = *(const f16x8*)(vrow + 0);
                const f16x8 vb1 = *(const f16x8*)(vrow + 16);
                acc[dt] = __builtin_amdgcn_mfma_f32_32x32x16_f16(pa[0].h, vb0, acc[dt], 0, 0, 0);
                acc[dt] = __builtin_amdgcn_mfma_f32_32x32x16_f16(pa[1].h, vb1, acc[dt], 0, 0, 0);
            }
        }
        if (kt + 1 < nkt) {
            writeLds(cur ^ 1);
            if (kt + 2 < nkt) issue(kt + 2);
            __syncthreads();
        }
    }
    float li[16];
    #pragma unroll
    for (int r = 0; r < 16; ++r) {
        const float lv = __shfl(l_i, (r & 3) + 8 * (r >> 2) + 4 * h);
        li[r] = 1.0f / lv;
    }
    #pragma unroll
    for (int dt = 0; dt < 4; ++dt)
        #pragma unroll
        for (int r = 0; r < 16; ++r) {
            const int row = qw0 + (r & 3) + 8 * (r >> 2) + 4 * h;
            Ob[(size_t)row * D_ + dt * 32 + l31] = acc[dt][r] * li[r];
        }
}

extern "C" void kernel_launch(void* const* d_in, const int* in_sizes, int n_in,
                              void* d_out, int out_size, void* d_ws, size_t ws_size,
                              hipStream_t stream) {
    (void)in_sizes; (void)n_in; (void)out_size;
    const float* Q = (const float*)d_in[0];
    const float* K = (const float*)d_in[1];
    const float* V = (const float*)d_in[2];
    float* O = (float*)d_out;
    const size_t elems     = (size_t)B_ * H_ * S_ * D_;
    const size_t nrow      = (size_t)B_ * H_ * S_;
    const size_t needKV    = elems * 2 * sizeof(f16);                       // Kh + Vtt
    const size_t needSplit = needKV + elems * 2 * sizeof(f16) + nrow * 2 * sizeof(float2);
    if (ws_size >= needSplit) {
        f16* Kh  = (f16*)d_ws;
        f16* Vtt = Kh + elems;
        f16* P   = Vtt + elems;                 // [2][bh][row][d]
        float2* ml = (float2*)(P + 2 * elems);  // [2][bh*S]
        prep<<<dim3(B_ * H_ * (S_ / 64)), dim3(256), 0, stream>>>(K, V, Kh, Vtt);
        fattn7<true><<<dim3(2 * (S_ / 128) * B_ * H_), dim3(256), 0, stream>>>(Q, Kh, Vtt, O, P, ml);
        merge<<<dim3(2048), dim3(256), 0, stream>>>(P, ml, O);
    } else if (ws_size >= needKV) {
        f16* Kh  = (f16*)d_ws;
        f16* Vtt = Kh + elems;
        prep<<<dim3(B_ * H_ * (S_ / 64)), dim3(256), 0, stream>>>(K, V, Kh, Vtt);
        fattn7<false><<<dim3((S_ / 128) * B_ * H_), dim3(256), 0, stream>>>(Q, Kh, Vtt, O, nullptr, nullptr);
    } else {
        fattn5<<<dim3((S_ / 128) * B_ * H_), dim3(256), 0, stream>>>(Q, K, V, O);
    }
}

// Round 10
// 177.062 us; speedup vs baseline: 4.4695x; 1.0506x over previous
//
#include <hip/hip_runtime.h>

typedef _Float16 f16;
typedef _Float16 f16x8 __attribute__((ext_vector_type(8)));
typedef float    f32x16 __attribute__((ext_vector_type(16)));
typedef int      i32x4 __attribute__((ext_vector_type(4)));

#define B_ 4
#define H_ 16
#define S_ 2048
#define D_ 128
#define KVB 32
#define KSTR 136      // 272B = 17x16B slots, 17%8=1 -> min-aliasing b128
#define VTSTR 40      // 80B  =  5x16B slots,  5%8=5 -> min-aliasing b128

union U4 { i32x4 i; f16x8 h; };

__device__ __forceinline__ unsigned pk2(float a, float b) {
    auto v = __builtin_amdgcn_cvt_pkrtz(a, b);
    return __builtin_bit_cast(unsigned, v);
}

__device__ __forceinline__ f16x8 cvt8(const float4 a, const float4 b) {
    f16x8 h;
    h[0] = (f16)a.x; h[1] = (f16)a.y; h[2] = (f16)a.z; h[3] = (f16)a.w;
    h[4] = (f16)b.x; h[5] = (f16)b.y; h[6] = (f16)b.z; h[7] = (f16)b.w;
    return h;
}

// ---------------- pre-pass: K -> f16 row-major; V -> f16 tile-transposed ----------------
// Vtt layout: [bh][kt=k/32][d][kk=k%32]  (one 32-key tile = contiguous 8KB)
__global__ __launch_bounds__(256)
void prep(const float* __restrict__ K, const float* __restrict__ V,
          f16* __restrict__ Kh, f16* __restrict__ Vtt)
{
    const int bid = blockIdx.x;
    const int bh  = bid >> 5;
    const int kb  = bid & 31;
    const int k0  = kb * 64;
    const int tid = threadIdx.x;

    const float* Kb = K + ((size_t)bh * S_ + k0) * D_;
    const float* Vb = V + ((size_t)bh * S_ + k0) * D_;
    f16* Khb = Kh + ((size_t)bh * S_ + k0) * D_;
    f16* Vtb = Vtt + (size_t)bh * S_ * D_ + (size_t)kb * 2 * (D_ * 32);

    #pragma unroll
    for (int it = 0; it < 4; ++it) {
        const int idx = tid + it * 256;
        const int row = idx >> 4, c8 = idx & 15;
        const float4 a = *(const float4*)(Kb + row * D_ + c8 * 8);
        const float4 b = *(const float4*)(Kb + row * D_ + c8 * 8 + 4);
        *(f16x8*)(Khb + row * D_ + c8 * 8) = cvt8(a, b);
    }
    #pragma unroll
    for (int it = 0; it < 4; ++it) {
        const int idx = tid + it * 256;
        const int d  = idx & 127;
        const int k8 = idx >> 7;
        const float* vp = Vb + (size_t)(k8 * 8) * D_ + d;
        f16x8 vh;
        #pragma unroll
        for (int e = 0; e < 8; ++e) vh[e] = (f16)vp[(size_t)e * D_];
        *(f16x8*)(Vtb + (size_t)(k8 >> 2) * (D_ * 32) + d * 32 + (k8 & 3) * 8) = vh;
    }
}

// ---------------- main kernel: paired q-tiles (p, 15-p) => uniform 68 tiles/block ----------------
__global__ __launch_bounds__(256, 3)
void fattn9(const float* __restrict__ Qg, const f16* __restrict__ Khg,
            const f16* __restrict__ Vttg, float* __restrict__ Og)
{
    __shared__ __align__(16) f16 Klds[2][KVB * KSTR];
    __shared__ __align__(16) f16 Vt[2][128 * VTSTR];

    // 512 blocks: xcd = id&7, bh = xcd + 8*(r&7), pair p = r>>3  (bh's blocks share an XCD)
    const int id  = blockIdx.x;
    const int xcd = id & 7;
    const int r   = id >> 3;
    const int bh  = xcd + 8 * (r & 7);
    const int p   = r >> 3;              // 0..7

    const int tid  = threadIdx.x;
    const int lane = tid & 63;
    const int l31  = lane & 31;
    const int h    = lane >> 5;
    const int wv   = tid >> 6;

    const float* Qb  = Qg   + (size_t)bh * S_ * D_;
    const f16*   Khb = Khg  + (size_t)bh * S_ * D_;
    const f16*   Vtb = Vttg + (size_t)bh * S_ * D_;
    float*       Ob  = Og   + (size_t)bh * S_ * D_;

    i32x4 kr[2], vr[2];
    auto issue = [&](int kt) {
        const int k0n = kt * KVB;
        #pragma unroll
        for (int it = 0; it < 2; ++it) {
            const int idx  = tid + it * 256;
            const int krow = idx >> 4, c8 = idx & 15;
            kr[it] = *(const i32x4*)(Khb + (size_t)(k0n + krow) * D_ + c8 * 8);
            vr[it] = *(const i32x4*)(Vtb + (size_t)kt * (D_ * 32) + (size_t)idx * 8);
        }
    };
    auto writeLds = [&](int buf) {
        #pragma unroll
        for (int it = 0; it < 2; ++it) {
            const int idx  = tid + it * 256;
            const int krow = idx >> 4, c8 = idx & 15;
            *(i32x4*)&Klds[buf][krow * KSTR + c8 * 8] = kr[it];
            const int d = idx >> 2, kk8 = idx & 3;
            *(i32x4*)&Vt[buf][d * VTSTR + kk8 * 8] = vr[it];
        }
    };

    const float qmul = 0.08838834764831845f * 1.4426950408889634f;  // 1/sqrt(128)*log2e

    #pragma unroll 1
    for (int ph = 0; ph < 2; ++ph) {
        const int qt  = ph ? 15 - p : p;
        const int qw0 = qt * 128 + wv * 32;
        const int qg  = qw0 + l31;
        const int nkt = 4 * qt + 4;

        issue(0);
        // Q fragments (B-operand: col=q=l31, k-dim d = dc*16 + 8h + j), pre-scaled
        f16x8 qf[8];
        {
            const float* Qrow = Qb + (size_t)(qw0 + l31) * D_;
            #pragma unroll
            for (int dc = 0; dc < 8; ++dc) {
                const float4 a = *(const float4*)(Qrow + dc * 16 + h * 8);
                const float4 b = *(const float4*)(Qrow + dc * 16 + h * 8 + 4);
                f16x8 q;
                q[0] = (f16)(a.x * qmul); q[1] = (f16)(a.y * qmul);
                q[2] = (f16)(a.z * qmul); q[3] = (f16)(a.w * qmul);
                q[4] = (f16)(b.x * qmul); q[5] = (f16)(b.y * qmul);
                q[6] = (f16)(b.z * qmul); q[7] = (f16)(b.w * qmul);
                qf[dc] = q;
            }
        }

        f32x16 acc[4];
        #pragma unroll
        for (int dt = 0; dt < 4; ++dt)
            #pragma unroll
            for (int rr = 0; rr < 16; ++rr) acc[dt][rr] = 0.f;
        float m_i = -1e30f, l_i = 0.f;

        __syncthreads();            // phase>0: all waves done reading prev phase's LDS
        writeLds(0);
        issue(1);
        __syncthreads();

        for (int kt = 0; kt < nkt; ++kt) {
            const int k0  = kt * KVB;
            const int cur = kt & 1;

            if (k0 <= qw0 + 31) {
                f32x16 sv;
                #pragma unroll
                for (int rr = 0; rr < 16; ++rr) sv[rr] = 0.f;
                __builtin_amdgcn_s_setprio(1);
                #pragma unroll
                for (int dc = 0; dc < 8; ++dc) {
                    const f16x8 kf = *(const f16x8*)&Klds[cur][l31 * KSTR + dc * 16 + h * 8];
                    sv = __builtin_amdgcn_mfma_f32_32x32x16_f16(kf, qf[dc], sv, 0, 0, 0);
                }
                __builtin_amdgcn_s_setprio(0);
                if (k0 + 31 > qw0) {
                    #pragma unroll
                    for (int rr = 0; rr < 16; ++rr) {
                        const int kg = k0 + (rr & 3) + 8 * (rr >> 2) + 4 * h;
                        if (kg > qg) sv[rr] = -1e30f;
                    }
                }
                // ---- row max: tree + proven shfl cross-half
                float t[8];
                #pragma unroll
                for (int rr = 0; rr < 8; ++rr) t[rr] = fmaxf(sv[2 * rr], sv[2 * rr + 1]);
                #pragma unroll
                for (int rr = 0; rr < 4; ++rr) t[rr] = fmaxf(t[rr], t[rr + 4]);
                t[0] = fmaxf(t[0], t[2]); t[1] = fmaxf(t[1], t[3]);
                float mx = fmaxf(t[0], t[1]);
                mx = fmaxf(mx, __shfl_xor(mx, 32));
                if (!__all(mx - m_i <= 8.0f)) {       // defer-max (T13)
                    const float mn = fmaxf(m_i, mx);
                    const float al = exp2f(m_i - mn);
                    m_i = mn;
                    l_i *= al;
                    float arow[16];
                    #pragma unroll
                    for (int rr = 0; rr < 16; ++rr)
                        arow[rr] = __shfl(al, (rr & 3) + 8 * (rr >> 2) + 4 * h);
                    #pragma unroll
                    for (int dt = 0; dt < 4; ++dt)
                        #pragma unroll
                        for (int rr = 0; rr < 16; ++rr) acc[dt][rr] *= arow[rr];
                }
                // ---- exp + row sum (tree) + shfl cross-half
                #pragma unroll
                for (int rr = 0; rr < 16; ++rr) sv[rr] = exp2f(sv[rr] - m_i);
                float s8[8];
                #pragma unroll
                for (int rr = 0; rr < 8; ++rr) s8[rr] = sv[2 * rr] + sv[2 * rr + 1];
                #pragma unroll
                for (int rr = 0; rr < 4; ++rr) s8[rr] += s8[rr + 4];
                s8[0] += s8[2]; s8[1] += s8[3];
                float rs = s8[0] + s8[1];
                rs += __shfl_xor(rs, 32);
                l_i += rs;
                // ---- P -> f16 A-frags (proven pack: pk2 + shfl_xor + cndmask)
                U4 pa[2];
                {
                    unsigned dwp[8];
                    #pragma unroll
                    for (int m = 0; m < 8; ++m) dwp[m] = pk2(sv[2 * m], sv[2 * m + 1]);
                    #pragma unroll
                    for (int hf = 0; hf < 2; ++hf) {
                        const unsigned a0 = dwp[hf * 4 + 0], a1 = dwp[hf * 4 + 1];
                        const unsigned b0 = dwp[hf * 4 + 2], b1 = dwp[hf * 4 + 3];
                        const unsigned sa0 = (unsigned)__shfl_xor((int)a0, 32);
                        const unsigned sa1 = (unsigned)__shfl_xor((int)a1, 32);
                        const unsigned sb0 = (unsigned)__shfl_xor((int)b0, 32);
                        const unsigned sb1 = (unsigned)__shfl_xor((int)b1, 32);
                        i32x4 d;
                        d[0] = h ? (int)sb0 : (int)a0;
                        d[1] = h ? (int)sb1 : (int)a1;
                        d[2] = h ? (int)b0  : (int)sa0;
                        d[3] = h ? (int)b1  : (int)sa1;
                        pa[hf].i = d;
                    }
                }
                // ---- PV
                __builtin_amdgcn_s_setprio(1);
                #pragma unroll
                for (int dt = 0; dt < 4; ++dt) {
                    const f16* vrow = &Vt[cur][(dt * 32 + l31) * VTSTR + h * 8];
                    const f16x8 vb0 = *(const f16x8*)(vrow + 0);
                    const f16x8 vb1 = *(const f16x8*)(vrow + 16);
                    acc[dt] = __builtin_amdgcn_mfma_f32_32x32x16_f16(pa[0].h, vb0, acc[dt], 0, 0, 0);
                    acc[dt] = __builtin_amdgcn_mfma_f32_32x32x16_f16(pa[1].h, vb1, acc[dt], 0, 0, 0);
                }
                __builtin_amdgcn_s_setprio(0);
            }

            if (kt + 1 < nkt) {
                writeLds(cur ^ 1);
                if (kt + 2 < nkt) issue(kt + 2);
                __syncthreads();
            }
        }

        // epilogue (row=(rr&3)+8*(rr>>2)+4h, col=dt*32+l31)
        float li[16];
        #pragma unroll
        for (int rr = 0; rr < 16; ++rr) {
            const float lv = __shfl(l_i, (rr & 3) + 8 * (rr >> 2) + 4 * h);
            li[rr] = 1.0f / lv;
        }
        #pragma unroll
        for (int dt = 0; dt < 4; ++dt)
            #pragma unroll
            for (int rr = 0; rr < 16; ++rr) {
                const int row = qw0 + (rr & 3) + 8 * (rr >> 2) + 4 * h;
                Ob[(size_t)row * D_ + dt * 32 + l31] = acc[dt][rr] * li[rr];
            }
    }
}

// ---------------- fallback (tiny ws): f32 in-loop staging, single pass ----------------
__global__ __launch_bounds__(256, 3)
void fattn5(const float* __restrict__ Qg, const float* __restrict__ Kg,
            const float* __restrict__ Vg, float* __restrict__ Og)
{
    __shared__ __align__(16) f16 Klds[2][KVB * KSTR];
    __shared__ __align__(16) f16 Vt[2][128 * VTSTR];
    const int id  = blockIdx.x;
    const int xcd = id & 7;
    const int w   = id >> 3;
    const int qt  = 15 - (w & 15);
    const int bh  = xcd + 8 * (w >> 4);
    const int tid  = threadIdx.x;
    const int lane = tid & 63;
    const int wv   = tid >> 6;
    const int l31  = lane & 31;
    const int h    = lane >> 5;
    const int qw0 = qt * 128 + wv * 32;
    const int qg  = qw0 + l31;
    const size_t base = (size_t)bh * S_ * D_;
    const float* Qb = Qg + base;
    const float* Kb = Kg + base;
    const float* Vb = Vg + base;
    float*       Ob = Og + base;
    const int nkt = 4 * qt + 4;
    float4 kr[4];
    float  vr[16];
    auto issue = [&](int kt) {
        const int k0n = kt * KVB;
        #pragma unroll
        for (int it = 0; it < 2; ++it) {
            const int idx  = tid + it * 256;
            const int krow = idx >> 4;
            const int c8   = idx & 15;
            const float* kp = Kb + (size_t)(k0n + krow) * D_ + c8 * 8;
            kr[it * 2]     = *(const float4*)kp;
            kr[it * 2 + 1] = *(const float4*)(kp + 4);
            const int d  = idx & 127;
            const int k8 = idx >> 7;
            const float* vp = Vb + (size_t)(k0n + k8 * 8) * D_ + d;
            #pragma unroll
            for (int e = 0; e < 8; ++e) vr[it * 8 + e] = vp[(size_t)e * D_];
        }
    };
    auto writeLds = [&](int buf) {
        #pragma unroll
        for (int it = 0; it < 2; ++it) {
            const int idx  = tid + it * 256;
            const int krow = idx >> 4;
            const int c8   = idx & 15;
            *(f16x8*)&Klds[buf][krow * KSTR + c8 * 8] = cvt8(kr[it * 2], kr[it * 2 + 1]);
            const int d  = idx & 127;
            const int k8 = idx >> 7;
            f16x8 vh;
            #pragma unroll
            for (int e = 0; e < 8; ++e) vh[e] = (f16)vr[it * 8 + e];
            *(f16x8*)&Vt[buf][d * VTSTR + k8 * 8] = vh;
        }
    };
    const float qmul = 0.08838834764831845f * 1.4426950408889634f;
    f16x8 qf[8];
    {
        const float* Qrow = Qb + (size_t)(qw0 + l31) * D_;
        #pragma unroll
        for (int dc = 0; dc < 8; ++dc) {
            const float4 a = *(const float4*)(Qrow + dc * 16 + h * 8);
            const float4 b = *(const float4*)(Qrow + dc * 16 + h * 8 + 4);
            f16x8 q;
            q[0] = (f16)(a.x * qmul); q[1] = (f16)(a.y * qmul);
            q[2] = (f16)(a.z * qmul); q[3] = (f16)(a.w * qmul);
            q[4] = (f16)(b.x * qmul); q[5] = (f16)(b.y * qmul);
            q[6] = (f16)(b.z * qmul); q[7] = (f16)(b.w * qmul);
            qf[dc] = q;
        }
    }
    f32x16 acc[4];
    #pragma unroll
    for (int dt = 0; dt < 4; ++dt)
        #pragma unroll
        for (int rr = 0; rr < 16; ++rr) acc[dt][rr] = 0.f;
    float m_i = -1e30f, l_i = 0.f;
    issue(0);
    writeLds(0);
    if (nkt > 1) issue(1);
    __syncthreads();
    for (int kt = 0; kt < nkt; ++kt) {
        const int k0  = kt * KVB;
        const int cur = kt & 1;
        if (k0 <= qw0 + 31) {
            f32x16 sv;
            #pragma unroll
            for (int rr = 0; rr < 16; ++rr) sv[rr] = 0.f;
            #pragma unroll
            for (int dc = 0; dc < 8; ++dc) {
                const f16x8 kf = *(const f16x8*)&Klds[cur][l31 * KSTR + dc * 16 + h * 8];
                sv = __builtin_amdgcn_mfma_f32_32x32x16_f16(kf, qf[dc], sv, 0, 0, 0);
            }
            if (k0 + 31 > qw0) {
                #pragma unroll
                for (int rr = 0; rr < 16; ++rr) {
                    const int kg = k0 + (rr & 3) + 8 * (rr >> 2) + 4 * h;
                    if (kg > qg) sv[rr] = -1e30f;
                }
            }
            float mx = sv[0];
            #pragma unroll
            for (int rr = 1; rr < 16; ++rr) mx = fmaxf(mx, sv[rr]);
            mx = fmaxf(mx, __shfl_xor(mx, 32));
            if (!__all(mx - m_i <= 8.0f)) {
                const float mn = fmaxf(m_i, mx);
                const float al = exp2f(m_i - mn);
                m_i = mn;
                l_i *= al;
                float arow[16];
                #pragma unroll
                for (int rr = 0; rr < 16; ++rr)
                    arow[rr] = __shfl(al, (rr & 3) + 8 * (rr >> 2) + 4 * h);
                #pragma unroll
                for (int dt = 0; dt < 4; ++dt)
                    #pragma unroll
                    for (int rr = 0; rr < 16; ++rr) acc[dt][rr] *= arow[rr];
            }
            float rs = 0.f;
            #pragma unroll
            for (int rr = 0; rr < 16; ++rr) {
                sv[rr] = exp2f(sv[rr] - m_i);
                rs += sv[rr];
            }
            rs += __shfl_xor(rs, 32);
            l_i += rs;
            U4 pa[2];
            {
                unsigned dwp[8];
                #pragma unroll
                for (int m = 0; m < 8; ++m) dwp[m] = pk2(sv[2 * m], sv[2 * m + 1]);
                #pragma unroll
                for (int hf = 0; hf < 2; ++hf) {
                    const unsigned a0 = dwp[hf * 4 + 0], a1 = dwp[hf * 4 + 1];
                    const unsigned b0 = dwp[hf * 4 + 2], b1 = dwp[hf * 4 + 3];
                    const unsigned sa0 = (unsigned)__shfl_xor((int)a0, 32);
                    const unsigned sa1 = (unsigned)__shfl_xor((int)a1, 32);
                    const unsigned sb0 = (unsigned)__shfl_xor((int)b0, 32);
                    const unsigned sb1 = (unsigned)__shfl_xor((int)b1, 32);
                    i32x4 d;
                    d[0] = h ? (int)sb0 : (int)a0;
                    d[1] = h ? (int)sb1 : (int)a1;
                    d[2] = h ? (int)b0  : (int)sa0;
                    d[3] = h ? (int)b1  : (int)sa1;
                    pa[hf].i = d;
                }
            }
            #pragma unroll
            for (int dt = 0; dt < 4; ++dt) {
                const f16* vrow = &Vt[cur][(dt * 32 + l31) * VTSTR + h * 8];
                const f16x8 vb0 = *(const f16x8*)(vrow + 0);
                const f16x8 vb1 = *(const f16x8*)(vrow + 16);
                acc[dt] = __builtin_amdgcn_mfma_f32_32x32x16_f16(pa[0].h, vb0, acc[dt], 0, 0, 0);
                acc[dt] = __builtin_amdgcn_mfma_f32_32x32x16_f16(pa[1].h, vb1, acc[dt], 0, 0, 0);
            }
        }
        if (kt + 1 < nkt) {
            writeLds(cur ^ 1);
            if (kt + 2 < nkt) issue(kt + 2);
            __syncthreads();
        }
    }
    float li[16];
    #pragma unroll
    for (int rr = 0; rr < 16; ++rr) {
        const float lv = __shfl(l_i, (rr & 3) + 8 * (rr >> 2) + 4 * h);
        li[rr] = 1.0f / lv;
    }
    #pragma unroll
    for (int dt = 0; dt < 4; ++dt)
        #pragma unroll
        for (int rr = 0; rr < 16; ++rr) {
            const int row = qw0 + (rr & 3) + 8 * (rr >> 2) + 4 * h;
            Ob[(size_t)row * D_ + dt * 32 + l31] = acc[dt][rr] * li[rr];
        }
}

extern "C" void kernel_launch(void* const* d_in, const int* in_sizes, int n_in,
                              void* d_out, int out_size, void* d_ws, size_t ws_size,
                              hipStream_t stream) {
    (void)in_sizes; (void)n_in; (void)out_size;
    const float* Q = (const float*)d_in[0];
    const float* K = (const float*)d_in[1];
    const float* V = (const float*)d_in[2];
    float* O = (float*)d_out;
    const size_t elems  = (size_t)B_ * H_ * S_ * D_;
    const size_t needKV = elems * 2 * sizeof(f16);     // Kh + Vtt
    if (ws_size >= needKV) {
        f16* Kh  = (f16*)d_ws;
        f16* Vtt = Kh + elems;
        prep<<<dim3(B_ * H_ * (S_ / 64)), dim3(256), 0, stream>>>(K, V, Kh, Vtt);
        fattn9<<<dim3(512), dim3(256), 0, stream>>>(Q, Kh, Vtt, O);
    } else {
        fattn5<<<dim3((S_ / 128) * B_ * H_), dim3(256), 0, stream>>>(Q, K, V, O);
    }
}

// Round 11
// 160.929 us; speedup vs baseline: 4.9176x; 1.1003x over previous
//
#include <hip/hip_runtime.h>

typedef _Float16 f16;
typedef _Float16 f16x8 __attribute__((ext_vector_type(8)));
typedef float    f32x16 __attribute__((ext_vector_type(16)));
typedef int      i32x4 __attribute__((ext_vector_type(4)));

#define B_ 4
#define H_ 16
#define S_ 2048
#define D_ 128
#define KVB 32
#define KSTR 136      // 272B = 17x16B slots, 17%8=1 -> min-aliasing b128
#define VTSTR 40      // 80B  =  5x16B slots,  5%8=5 -> min-aliasing b128

union U4 { i32x4 i; f16x8 h; };

__device__ __forceinline__ unsigned pk2(float a, float b) {
    auto v = __builtin_amdgcn_cvt_pkrtz(a, b);
    return __builtin_bit_cast(unsigned, v);
}

__device__ __forceinline__ f16x8 cvt8(const float4 a, const float4 b) {
    f16x8 h;
    h[0] = (f16)a.x; h[1] = (f16)a.y; h[2] = (f16)a.z; h[3] = (f16)a.w;
    h[4] = (f16)b.x; h[5] = (f16)b.y; h[6] = (f16)b.z; h[7] = (f16)b.w;
    return h;
}

// ---------------- pre-pass: K -> f16 row-major; V -> f16 tile-transposed ----------------
// Vtt layout: [bh][kt=k/32][d][kk=k%32]  (one 32-key tile = contiguous 8KB)
__global__ __launch_bounds__(256)
void prep(const float* __restrict__ K, const float* __restrict__ V,
          f16* __restrict__ Kh, f16* __restrict__ Vtt)
{
    const int bid = blockIdx.x;
    const int bh  = bid >> 5;
    const int kb  = bid & 31;
    const int k0  = kb * 64;
    const int tid = threadIdx.x;

    const float* Kb = K + ((size_t)bh * S_ + k0) * D_;
    const float* Vb = V + ((size_t)bh * S_ + k0) * D_;
    f16* Khb = Kh + ((size_t)bh * S_ + k0) * D_;
    f16* Vtb = Vtt + (size_t)bh * S_ * D_ + (size_t)kb * 2 * (D_ * 32);

    #pragma unroll
    for (int it = 0; it < 4; ++it) {
        const int idx = tid + it * 256;
        const int row = idx >> 4, c8 = idx & 15;
        const float4 a = *(const float4*)(Kb + row * D_ + c8 * 8);
        const float4 b = *(const float4*)(Kb + row * D_ + c8 * 8 + 4);
        *(f16x8*)(Khb + row * D_ + c8 * 8) = cvt8(a, b);
    }
    #pragma unroll
    for (int it = 0; it < 4; ++it) {
        const int idx = tid + it * 256;
        const int d  = idx & 127;
        const int k8 = idx >> 7;
        const float* vp = Vb + (size_t)(k8 * 8) * D_ + d;
        f16x8 vh;
        #pragma unroll
        for (int e = 0; e < 8; ++e) vh[e] = (f16)vp[(size_t)e * D_];
        *(f16x8*)(Vtb + (size_t)(k8 >> 2) * (D_ * 32) + d * 32 + (k8 & 3) * 8) = vh;
    }
}

// ------- main: paired q-tiles (p,15-p), dual-stream pipeline (QKT(t+1) || softmax+PV(t)) -------
__global__ __launch_bounds__(256, 2)
void fattn10(const float* __restrict__ Qg, const f16* __restrict__ Khg,
             const f16* __restrict__ Vttg, float* __restrict__ Og)
{
    __shared__ __align__(16) f16 Klds[2][KVB * KSTR];
    __shared__ __align__(16) f16 Vt[2][128 * VTSTR];

    // 512 blocks: xcd = id&7, bh = xcd + 8*(r&7), pair p = r>>3
    const int id  = blockIdx.x;
    const int xcd = id & 7;
    const int r   = id >> 3;
    const int bh  = xcd + 8 * (r & 7);
    const int p   = r >> 3;              // 0..7

    const int tid  = threadIdx.x;
    const int lane = tid & 63;
    const int l31  = lane & 31;
    const int h    = lane >> 5;
    const int wv   = tid >> 6;

    const float* Qb  = Qg   + (size_t)bh * S_ * D_;
    const f16*   Khb = Khg  + (size_t)bh * S_ * D_;
    const f16*   Vtb = Vttg + (size_t)bh * S_ * D_;
    float*       Ob  = Og   + (size_t)bh * S_ * D_;

    i32x4 kr[2], vr[2];
    auto issue = [&](int kt) {
        const int k0n = kt * KVB;
        #pragma unroll
        for (int it = 0; it < 2; ++it) {
            const int idx  = tid + it * 256;
            const int krow = idx >> 4, c8 = idx & 15;
            kr[it] = *(const i32x4*)(Khb + (size_t)(k0n + krow) * D_ + c8 * 8);
            vr[it] = *(const i32x4*)(Vtb + (size_t)kt * (D_ * 32) + (size_t)idx * 8);
        }
    };
    auto writeLds = [&](int buf) {
        #pragma unroll
        for (int it = 0; it < 2; ++it) {
            const int idx  = tid + it * 256;
            const int krow = idx >> 4, c8 = idx & 15;
            *(i32x4*)&Klds[buf][krow * KSTR + c8 * 8] = kr[it];
            const int d = idx >> 2, kk8 = idx & 3;
            *(i32x4*)&Vt[buf][d * VTSTR + kk8 * 8] = vr[it];
        }
    };
    f16x8 qf[8];
    auto qkt = [&](int buf) {
        f32x16 a;
        #pragma unroll
        for (int rr = 0; rr < 16; ++rr) a[rr] = 0.f;
        #pragma unroll
        for (int dc = 0; dc < 8; ++dc) {
            const f16x8 kf = *(const f16x8*)&Klds[buf][l31 * KSTR + dc * 16 + h * 8];
            a = __builtin_amdgcn_mfma_f32_32x32x16_f16(kf, qf[dc], a, 0, 0, 0);
        }
        return a;
    };

    const float qmul = 0.08838834764831845f * 1.4426950408889634f;  // 1/sqrt(128)*log2e

    #pragma unroll 1
    for (int ph = 0; ph < 2; ++ph) {
        const int qt  = ph ? 15 - p : p;
        const int qw0 = qt * 128 + wv * 32;
        const int qg  = qw0 + l31;
        const int nkt = 4 * qt + 4;

        issue(0);
        {
            const float* Qrow = Qb + (size_t)(qw0 + l31) * D_;
            #pragma unroll
            for (int dc = 0; dc < 8; ++dc) {
                const float4 a = *(const float4*)(Qrow + dc * 16 + h * 8);
                const float4 b = *(const float4*)(Qrow + dc * 16 + h * 8 + 4);
                f16x8 q;
                q[0] = (f16)(a.x * qmul); q[1] = (f16)(a.y * qmul);
                q[2] = (f16)(a.z * qmul); q[3] = (f16)(a.w * qmul);
                q[4] = (f16)(b.x * qmul); q[5] = (f16)(b.y * qmul);
                q[6] = (f16)(b.z * qmul); q[7] = (f16)(b.w * qmul);
                qf[dc] = q;
            }
        }

        f32x16 acc[4];
        #pragma unroll
        for (int dt = 0; dt < 4; ++dt)
            #pragma unroll
            for (int rr = 0; rr < 16; ++rr) acc[dt][rr] = 0.f;
        float m_i = -1e30f, l_i = 0.f;

        __syncthreads();            // prev phase's waves done reading LDS
        writeLds(0);
        issue(1);
        __syncthreads();            // buf0 ready

        f32x16 sv = qkt(0);         // tile 0 scores in flight

        for (int kt = 0; kt < nkt; ++kt) {
            const int cur  = kt & 1;
            const bool more = (kt + 1 < nkt);

            if (more) {
                __syncthreads();            // all waves done: QKT(kt)[buf cur], PV(kt-1)[buf cur^1]
                writeLds(cur ^ 1);          // tile kt+1 -> LDS (vmcnt covered by last compute)
                if (kt + 2 < nkt) issue(kt + 2);
                __syncthreads();            // buf cur^1 (tile kt+1) ready
            }

            __builtin_amdgcn_s_setprio(1);
            // ---- stream A: QK^T for tile kt+1 (independent MFMAs)
            f32x16 svn;
            if (more) svn = qkt(cur ^ 1);

            // ---- stream B: softmax + pack + PV for tile kt
            const int k0 = kt * KVB;
            if (k0 + 31 > qw0) {
                #pragma unroll
                for (int rr = 0; rr < 16; ++rr) {
                    const int kg = k0 + (rr & 3) + 8 * (rr >> 2) + 4 * h;
                    if (kg > qg) sv[rr] = -1e30f;
                }
            }
            // row max: tree + shfl cross-half
            float t[8];
            #pragma unroll
            for (int rr = 0; rr < 8; ++rr) t[rr] = fmaxf(sv[2 * rr], sv[2 * rr + 1]);
            #pragma unroll
            for (int rr = 0; rr < 4; ++rr) t[rr] = fmaxf(t[rr], t[rr + 4]);
            t[0] = fmaxf(t[0], t[2]); t[1] = fmaxf(t[1], t[3]);
            float mx = fmaxf(t[0], t[1]);
            mx = fmaxf(mx, __shfl_xor(mx, 32));
            if (!__all(mx - m_i <= 8.0f)) {       // defer-max (T13)
                const float mn = fmaxf(m_i, mx);
                const float al = exp2f(m_i - mn);
                m_i = mn;
                l_i *= al;
                float arow[16];
                #pragma unroll
                for (int rr = 0; rr < 16; ++rr)
                    arow[rr] = __shfl(al, (rr & 3) + 8 * (rr >> 2) + 4 * h);
                #pragma unroll
                for (int dt = 0; dt < 4; ++dt)
                    #pragma unroll
                    for (int rr = 0; rr < 16; ++rr) acc[dt][rr] *= arow[rr];
            }
            // exp + row sum (tree) + shfl cross-half
            #pragma unroll
            for (int rr = 0; rr < 16; ++rr) sv[rr] = exp2f(sv[rr] - m_i);
            float s8[8];
            #pragma unroll
            for (int rr = 0; rr < 8; ++rr) s8[rr] = sv[2 * rr] + sv[2 * rr + 1];
            #pragma unroll
            for (int rr = 0; rr < 4; ++rr) s8[rr] += s8[rr + 4];
            s8[0] += s8[2]; s8[1] += s8[3];
            float rs = s8[0] + s8[1];
            rs += __shfl_xor(rs, 32);
            l_i += rs;
            // P -> f16 A-frags (proven pack: pk2 + shfl_xor + cndmask)
            U4 pa[2];
            {
                unsigned dwp[8];
                #pragma unroll
                for (int m = 0; m < 8; ++m) dwp[m] = pk2(sv[2 * m], sv[2 * m + 1]);
                #pragma unroll
                for (int hf = 0; hf < 2; ++hf) {
                    const unsigned a0 = dwp[hf * 4 + 0], a1 = dwp[hf * 4 + 1];
                    const unsigned b0 = dwp[hf * 4 + 2], b1 = dwp[hf * 4 + 3];
                    const unsigned sa0 = (unsigned)__shfl_xor((int)a0, 32);
                    const unsigned sa1 = (unsigned)__shfl_xor((int)a1, 32);
                    const unsigned sb0 = (unsigned)__shfl_xor((int)b0, 32);
                    const unsigned sb1 = (unsigned)__shfl_xor((int)b1, 32);
                    i32x4 d;
                    d[0] = h ? (int)sb0 : (int)a0;
                    d[1] = h ? (int)sb1 : (int)a1;
                    d[2] = h ? (int)b0  : (int)sa0;
                    d[3] = h ? (int)b1  : (int)sa1;
                    pa[hf].i = d;
                }
            }
            // PV (tile kt, buf cur)
            #pragma unroll
            for (int dt = 0; dt < 4; ++dt) {
                const f16* vrow = &Vt[cur][(dt * 32 + l31) * VTSTR + h * 8];
                const f16x8 vb0 = *(const f16x8*)(vrow + 0);
                const f16x8 vb1 = *(const f16x8*)(vrow + 16);
                acc[dt] = __builtin_amdgcn_mfma_f32_32x32x16_f16(pa[0].h, vb0, acc[dt], 0, 0, 0);
                acc[dt] = __builtin_amdgcn_mfma_f32_32x32x16_f16(pa[1].h, vb1, acc[dt], 0, 0, 0);
            }
            __builtin_amdgcn_s_setprio(0);

            if (more) sv = svn;
        }

        // epilogue (row=(rr&3)+8*(rr>>2)+4h, col=dt*32+l31)
        float li[16];
        #pragma unroll
        for (int rr = 0; rr < 16; ++rr) {
            const float lv = __shfl(l_i, (rr & 3) + 8 * (rr >> 2) + 4 * h);
            li[rr] = 1.0f / lv;
        }
        #pragma unroll
        for (int dt = 0; dt < 4; ++dt)
            #pragma unroll
            for (int rr = 0; rr < 16; ++rr) {
                const int row = qw0 + (rr & 3) + 8 * (rr >> 2) + 4 * h;
                Ob[(size_t)row * D_ + dt * 32 + l31] = acc[dt][rr] * li[rr];
            }
    }
}

// ---------------- fallback (tiny ws): f32 in-loop staging, single pass ----------------
__global__ __launch_bounds__(256, 3)
void fattn5(const float* __restrict__ Qg, const float* __restrict__ Kg,
            const float* __restrict__ Vg, float* __restrict__ Og)
{
    __shared__ __align__(16) f16 Klds[2][KVB * KSTR];
    __shared__ __align__(16) f16 Vt[2][128 * VTSTR];
    const int id  = blockIdx.x;
    const int xcd = id & 7;
    const int w   = id >> 3;
    const int qt  = 15 - (w & 15);
    const int bh  = xcd + 8 * (w >> 4);
    const int tid  = threadIdx.x;
    const int lane = tid & 63;
    const int wv   = tid >> 6;
    const int l31  = lane & 31;
    const int h    = lane >> 5;
    const int qw0 = qt * 128 + wv * 32;
    const int qg  = qw0 + l31;
    const size_t base = (size_t)bh * S_ * D_;
    const float* Qb = Qg + base;
    const float* Kb = Kg + base;
    const float* Vb = Vg + base;
    float*       Ob = Og + base;
    const int nkt = 4 * qt + 4;
    float4 kr[4];
    float  vr[16];
    auto issue = [&](int kt) {
        const int k0n = kt * KVB;
        #pragma unroll
        for (int it = 0; it < 2; ++it) {
            const int idx  = tid + it * 256;
            const int krow = idx >> 4;
            const int c8   = idx & 15;
            const float* kp = Kb + (size_t)(k0n + krow) * D_ + c8 * 8;
            kr[it * 2]     = *(const float4*)kp;
            kr[it * 2 + 1] = *(const float4*)(kp + 4);
            const int d  = idx & 127;
            const int k8 = idx >> 7;
            const float* vp = Vb + (size_t)(k0n + k8 * 8) * D_ + d;
            #pragma unroll
            for (int e = 0; e < 8; ++e) vr[it * 8 + e] = vp[(size_t)e * D_];
        }
    };
    auto writeLds = [&](int buf) {
        #pragma unroll
        for (int it = 0; it < 2; ++it) {
            const int idx  = tid + it * 256;
            const int krow = idx >> 4;
            const int c8   = idx & 15;
            *(f16x8*)&Klds[buf][krow * KSTR + c8 * 8] = cvt8(kr[it * 2], kr[it * 2 + 1]);
            const int d  = idx & 127;
            const int k8 = idx >> 7;
            f16x8 vh;
            #pragma unroll
            for (int e = 0; e < 8; ++e) vh[e] = (f16)vr[it * 8 + e];
            *(f16x8*)&Vt[buf][d * VTSTR + k8 * 8] = vh;
        }
    };
    const float qmul = 0.08838834764831845f * 1.4426950408889634f;
    f16x8 qf[8];
    {
        const float* Qrow = Qb + (size_t)(qw0 + l31) * D_;
        #pragma unroll
        for (int dc = 0; dc < 8; ++dc) {
            const float4 a = *(const float4*)(Qrow + dc * 16 + h * 8);
            const float4 b = *(const float4*)(Qrow + dc * 16 + h * 8 + 4);
            f16x8 q;
            q[0] = (f16)(a.x * qmul); q[1] = (f16)(a.y * qmul);
            q[2] = (f16)(a.z * qmul); q[3] = (f16)(a.w * qmul);
            q[4] = (f16)(b.x * qmul); q[5] = (f16)(b.y * qmul);
            q[6] = (f16)(b.z * qmul); q[7] = (f16)(b.w * qmul);
            qf[dc] = q;
        }
    }
    f32x16 acc[4];
    #pragma unroll
    for (int dt = 0; dt < 4; ++dt)
        #pragma unroll
        for (int rr = 0; rr < 16; ++rr) acc[dt][rr] = 0.f;
    float m_i = -1e30f, l_i = 0.f;
    issue(0);
    writeLds(0);
    if (nkt > 1) issue(1);
    __syncthreads();
    for (int kt = 0; kt < nkt; ++kt) {
        const int k0  = kt * KVB;
        const int cur = kt & 1;
        if (k0 <= qw0 + 31) {
            f32x16 sv;
            #pragma unroll
            for (int rr = 0; rr < 16; ++rr) sv[rr] = 0.f;
            #pragma unroll
            for (int dc = 0; dc < 8; ++dc) {
                const f16x8 kf = *(const f16x8*)&Klds[cur][l31 * KSTR + dc * 16 + h * 8];
                sv = __builtin_amdgcn_mfma_f32_32x32x16_f16(kf, qf[dc], sv, 0, 0, 0);
            }
            if (k0 + 31 > qw0) {
                #pragma unroll
                for (int rr = 0; rr < 16; ++rr) {
                    const int kg = k0 + (rr & 3) + 8 * (rr >> 2) + 4 * h;
                    if (kg > qg) sv[rr] = -1e30f;
                }
            }
            float mx = sv[0];
            #pragma unroll
            for (int rr = 1; rr < 16; ++rr) mx = fmaxf(mx, sv[rr]);
            mx = fmaxf(mx, __shfl_xor(mx, 32));
            if (!__all(mx - m_i <= 8.0f)) {
                const float mn = fmaxf(m_i, mx);
                const float al = exp2f(m_i - mn);
                m_i = mn;
                l_i *= al;
                float arow[16];
                #pragma unroll
                for (int rr = 0; rr < 16; ++rr)
                    arow[rr] = __shfl(al, (rr & 3) + 8 * (rr >> 2) + 4 * h);
                #pragma unroll
                for (int dt = 0; dt < 4; ++dt)
                    #pragma unroll
                    for (int rr = 0; rr < 16; ++rr) acc[dt][rr] *= arow[rr];
            }
            float rs = 0.f;
            #pragma unroll
            for (int rr = 0; rr < 16; ++rr) {
                sv[rr] = exp2f(sv[rr] - m_i);
                rs += sv[rr];
            }
            rs += __shfl_xor(rs, 32);
            l_i += rs;
            U4 pa[2];
            {
                unsigned dwp[8];
                #pragma unroll
                for (int m = 0; m < 8; ++m) dwp[m] = pk2(sv[2 * m], sv[2 * m + 1]);
                #pragma unroll
                for (int hf = 0; hf < 2; ++hf) {
                    const unsigned a0 = dwp[hf * 4 + 0], a1 = dwp[hf * 4 + 1];
                    const unsigned b0 = dwp[hf * 4 + 2], b1 = dwp[hf * 4 + 3];
                    const unsigned sa0 = (unsigned)__shfl_xor((int)a0, 32);
                    const unsigned sa1 = (unsigned)__shfl_xor((int)a1, 32);
                    const unsigned sb0 = (unsigned)__shfl_xor((int)b0, 32);
                    const unsigned sb1 = (unsigned)__shfl_xor((int)b1, 32);
                    i32x4 d;
                    d[0] = h ? (int)sb0 : (int)a0;
                    d[1] = h ? (int)sb1 : (int)a1;
                    d[2] = h ? (int)b0  : (int)sa0;
                    d[3] = h ? (int)b1  : (int)sa1;
                    pa[hf].i = d;
                }
            }
            #pragma unroll
            for (int dt = 0; dt < 4; ++dt) {
                const f16* vrow = &Vt[cur][(dt * 32 + l31) * VTSTR + h * 8];
                const f16x8 vb0 = *(const f16x8*)(vrow + 0);
                const f16x8 vb1 = *(const f16x8*)(vrow + 16);
                acc[dt] = __builtin_amdgcn_mfma_f32_32x32x16_f16(pa[0].h, vb0, acc[dt], 0, 0, 0);
                acc[dt] = __builtin_amdgcn_mfma_f32_32x32x16_f16(pa[1].h, vb1, acc[dt], 0, 0, 0);
            }
        }
        if (kt + 1 < nkt) {
            writeLds(cur ^ 1);
            if (kt + 2 < nkt) issue(kt + 2);
            __syncthreads();
        }
    }
    float li[16];
    #pragma unroll
    for (int rr = 0; rr < 16; ++rr) {
        const float lv = __shfl(l_i, (rr & 3) + 8 * (rr >> 2) + 4 * h);
        li[rr] = 1.0f / lv;
    }
    #pragma unroll
    for (int dt = 0; dt < 4; ++dt)
        #pragma unroll
        for (int rr = 0; rr < 16; ++rr) {
            const int row = qw0 + (rr & 3) + 8 * (rr >> 2) + 4 * h;
            Ob[(size_t)row * D_ + dt * 32 + l31] = acc[dt][rr] * li[rr];
        }
}

extern "C" void kernel_launch(void* const* d_in, const int* in_sizes, int n_in,
                              void* d_out, int out_size, void* d_ws, size_t ws_size,
                              hipStream_t stream) {
    (void)in_sizes; (void)n_in; (void)out_size;
    const float* Q = (const float*)d_in[0];
    const float* K = (const float*)d_in[1];
    const float* V = (const float*)d_in[2];
    float* O = (float*)d_out;
    const size_t elems  = (size_t)B_ * H_ * S_ * D_;
    const size_t needKV = elems * 2 * sizeof(f16);     // Kh + Vtt
    if (ws_size >= needKV) {
        f16* Kh  = (f16*)d_ws;
        f16* Vtt = Kh + elems;
        prep<<<dim3(B_ * H_ * (S_ / 64)), dim3(256), 0, stream>>>(K, V, Kh, Vtt);
        fattn10<<<dim3(512), dim3(256), 0, stream>>>(Q, Kh, Vtt, O);
    } else {
        fattn5<<<dim3((S_ / 128) * B_ * H_), dim3(256), 0, stream>>>(Q, K, V, O);
    }
}